// Round 17
// baseline (651.196 us; speedup 1.0000x reference)
//
#include <hip/hip_runtime.h>
#include <hip/hip_cooperative_groups.h>
#include <stdint.h>

namespace cg = cooperative_groups;

#define T_ 8
#define N_ 4096
#define E_ 131072

typedef __attribute__((ext_vector_type(4))) float f32x4;
typedef __attribute__((ext_vector_type(8))) short s16x8;
typedef __attribute__((ext_vector_type(4))) short s16x4;

static __device__ __forceinline__ short f2bf(float f) {
    union { float f; unsigned u; } v; v.f = f;
    unsigned r = v.u + 0x7fffu + ((v.u >> 16) & 1u);   // RNE
    return (short)(r >> 16);
}
static __device__ __forceinline__ float bf2f(short s) {
    union { float f; unsigned u; } v; v.u = ((unsigned)(unsigned short)s) << 16;
    return v.f;
}

// barrier that does NOT drain vmcnt (validated round 14)
static __device__ __forceinline__ void bar_nodrain() {
    asm volatile("s_waitcnt lgkmcnt(0)\n\ts_barrier" ::: "memory");
}

// ---------------- Yt[t][j][n] (bf16) = X[t][n][j] transposed, j in [0,128) ----------------
__global__ __launch_bounds__(256) void pack_yt(const float* __restrict__ feat,
                                               short* __restrict__ yt) {
    __shared__ float tile[32][33];
    const int t = blockIdx.z, j0 = blockIdx.y * 32, n0 = blockIdx.x * 32;
    const float* src = feat + (size_t)t * N_ * 128 + j0;
    const int jj = threadIdx.x & 31, i4 = threadIdx.x >> 5;
#pragma unroll
    for (int s = 0; s < 4; s++) {
        int ii = i4 * 4 + s;
        tile[ii][jj] = src[(size_t)(n0 + ii) * 128 + jj];
    }
    __syncthreads();
    const int nn = threadIdx.x & 31, j4 = threadIdx.x >> 5;
#pragma unroll
    for (int s = 0; s < 4; s++) {
        int j2 = j4 * 4 + s;
        yt[(size_t)(t * 128 + j0 + j2) * N_ + n0 + nn] = f2bf(tile[nn][j2]);
    }
}

// ---------------- PX[t] = P[t] @ X[t]   (bf16 MFMA, fp32 acc; N=128) ----------------
__global__ __launch_bounds__(512) void pfy_gemm(const float* __restrict__ P,
                                                const short* __restrict__ Yt,
                                                float* __restrict__ Z) {
    __shared__ short As[2][128][72];   // [buf][row][k], 144B stride
    __shared__ short Bs[2][128][72];   // [buf][col][k]
    const int t = blockIdx.y;
    const int m0 = blockIdx.x * 128;
    const int tid = threadIdx.x;
    const int lane = tid & 63, wid = tid >> 6;
    const int wm = wid >> 2, wn = wid & 3;       // wave grid 2(M) x 4(N)
    const int frow = lane & 15, kq = lane >> 4;  // MFMA fragment coords

    const float* Pt = P + (size_t)t * N_ * N_;
    const short* Bt = Yt + (size_t)t * 128 * N_;

    const int ar = tid >> 2;           // A row 0..127
    const int ak16 = (tid & 3) * 16;   // k offset (floats)
    const int bj = tid >> 2;           // B row 0..127
    const int bk16 = (tid & 3) * 16;   // k offset (shorts)

    f32x4 acc[4][2];
    f32x4 zf = {0.f, 0.f, 0.f, 0.f};
#pragma unroll
    for (int m = 0; m < 4; m++)
#pragma unroll
        for (int n = 0; n < 2; n++) acc[m][n] = zf;

    f32x4 aA[4], aB[4]; s16x8 bA[2], bB[2];

    const float* Pr = &Pt[(size_t)(m0 + ar) * 4096 + ak16];
    const short* Br = &Bt[(size_t)bj * 4096 + bk16];

#define LOADA(KT) do { const int k0_ = (KT) * 64;                              \
        _Pragma("unroll") for (int i = 0; i < 4; i++)                          \
            aA[i] = *(const f32x4*)&Pr[k0_ + i * 4];                           \
        _Pragma("unroll") for (int i = 0; i < 2; i++)                          \
            bA[i] = *(const s16x8*)&Br[k0_ + i * 8]; } while (0)
#define LOADB(KT) do { const int k0_ = (KT) * 64;                              \
        _Pragma("unroll") for (int i = 0; i < 4; i++)                          \
            aB[i] = *(const f32x4*)&Pr[k0_ + i * 4];                           \
        _Pragma("unroll") for (int i = 0; i < 2; i++)                          \
            bB[i] = *(const s16x8*)&Br[k0_ + i * 8]; } while (0)
#define STOREA(BUF) do {                                                       \
        _Pragma("unroll") for (int i = 0; i < 4; i++) {                        \
            s16x4 c4_;                                                         \
            _Pragma("unroll") for (int j = 0; j < 4; j++) c4_[j] = f2bf(aA[i][j]); \
            *(s16x4*)&As[BUF][ar][ak16 + i * 4] = c4_; }                       \
        _Pragma("unroll") for (int i = 0; i < 2; i++)                          \
            *(s16x8*)&Bs[BUF][bj][bk16 + i * 8] = bA[i]; } while (0)
#define STOREB(BUF) do {                                                       \
        _Pragma("unroll") for (int i = 0; i < 4; i++) {                        \
            s16x4 c4_;                                                         \
            _Pragma("unroll") for (int j = 0; j < 4; j++) c4_[j] = f2bf(aB[i][j]); \
            *(s16x4*)&As[BUF][ar][ak16 + i * 4] = c4_; }                       \
        _Pragma("unroll") for (int i = 0; i < 2; i++)                          \
            *(s16x8*)&Bs[BUF][bj][bk16 + i * 8] = bB[i]; } while (0)

    auto compute_t = [&](int buf) {
#pragma unroll
        for (int ks = 0; ks < 2; ks++) {
            s16x8 af[4], bfr[2];
#pragma unroll
            for (int m = 0; m < 4; m++)
                af[m] = *(const s16x8*)&As[buf][wm * 64 + m * 16 + frow][kq * 8 + ks * 32];
#pragma unroll
            for (int n = 0; n < 2; n++)
                bfr[n] = *(const s16x8*)&Bs[buf][wn * 32 + n * 16 + frow][kq * 8 + ks * 32];
#pragma unroll
            for (int m = 0; m < 4; m++)
#pragma unroll
                for (int n = 0; n < 2; n++)
                    acc[m][n] = __builtin_amdgcn_mfma_f32_16x16x32_bf16(af[m], bfr[n], acc[m][n], 0, 0, 0);
        }
    };

    LOADA(0);
    STOREA(0);
    LOADB(1);
    LOADA(2);
    bar_nodrain();

#pragma unroll 2
    for (int kt = 0; kt < 64; kt++) {
        compute_t(kt & 1);
        if (kt < 63) {
            if ((kt & 1) == 0) {
                STOREB(1);
                if (kt + 3 < 64) LOADB(kt + 3);
            } else {
                STOREA(0);
                if (kt + 3 < 64) LOADA(kt + 3);
            }
            bar_nodrain();
        }
    }
#undef LOADA
#undef LOADB
#undef STOREA
#undef STOREB

    float* Zt = Z + (size_t)t * N_ * 128;
#pragma unroll
    for (int m = 0; m < 4; m++)
#pragma unroll
        for (int n = 0; n < 2; n++)
#pragma unroll
            for (int r = 0; r < 4; r++) {
                int row = m0 + wm * 64 + m * 16 + kq * 4 + r;  // C/D: row=(lane>>4)*4+reg
                int col = wn * 32 + n * 16 + frow;             //      col=lane&15
                Zt[(size_t)row * 128 + col] = acc[m][n][r];
            }
}

// ---------------- filter heads: mode 0: low = relu(PX@Wlp + b_lpf) -> xseq[:, :128]
//                  mode 1: high = relu((X-PX)@Whp + b_hpf) -> xseq[:, 128:]
__global__ __launch_bounds__(256) void hp2_gemm(const float* __restrict__ feat,
                                                const float* __restrict__ PX,
                                                const float* __restrict__ Wlp,
                                                const float* __restrict__ Whp,
                                                const float* __restrict__ b_lpf,
                                                const float* __restrict__ b_hpf,
                                                short* __restrict__ xhi,
                                                short* __restrict__ xlo) {
    __shared__ float As[32][68];
    __shared__ float Ws[32][132];
    const int m0 = blockIdx.x * 64;
    const int mode = blockIdx.y;            // 0 = low, 1 = high
    const float* W = mode ? Whp : Wlp;
    const float* bp = mode ? b_hpf : b_lpf;
    const int tid = threadIdx.x;
    const int rg = tid & 15, cg2 = tid >> 4;
    float acc[4][8];
#pragma unroll
    for (int r = 0; r < 4; r++)
#pragma unroll
        for (int c = 0; c < 8; c++) acc[r][c] = 0.f;

    for (int k0 = 0; k0 < 128; k0 += 32) {
#pragma unroll
        for (int s = 0; s < 2; s++) {
            int q = tid + s * 256, row = q >> 3, k4 = q & 7;
            f32x4 pv = *(const f32x4*)&PX[(size_t)(m0 + row) * 128 + k0 + k4 * 4];
            f32x4 v;
            if (mode) {
                f32x4 fv = *(const f32x4*)&feat[(size_t)(m0 + row) * 128 + k0 + k4 * 4];
#pragma unroll
                for (int i = 0; i < 4; i++) v[i] = fv[i] - pv[i];
            } else {
                v = pv;
            }
#pragma unroll
            for (int i = 0; i < 4; i++) As[k4 * 4 + i][row] = v[i];
        }
#pragma unroll
        for (int s = 0; s < 4; s++) {
            int q = tid + s * 256, kk = q >> 5, j4 = q & 31;
            *(f32x4*)&Ws[kk][j4 * 4] = *(const f32x4*)&W[(size_t)(k0 + kk) * 128 + j4 * 4];
        }
        __syncthreads();
#pragma unroll
        for (int kk = 0; kk < 32; kk++) {
            f32x4 a  = *(const f32x4*)&As[kk][rg * 4];
            f32x4 w0 = *(const f32x4*)&Ws[kk][cg2 * 8];
            f32x4 w1 = *(const f32x4*)&Ws[kk][cg2 * 8 + 4];
#pragma unroll
            for (int r = 0; r < 4; r++)
#pragma unroll
                for (int c = 0; c < 4; c++) {
                    acc[r][c]     += a[r] * w0[c];
                    acc[r][c + 4] += a[r] * w1[c];
                }
        }
        __syncthreads();
    }
    float bh[8];
#pragma unroll
    for (int c = 0; c < 8; c++) bh[c] = bp[cg2 * 8 + c];
#pragma unroll
    for (int r = 0; r < 4; r++) {
        s16x4 h0, h1, l0, l1;
#pragma unroll
        for (int c = 0; c < 4; c++) {
            float v0 = fmaxf(acc[r][c] + bh[c], 0.f);
            float v1 = fmaxf(acc[r][c + 4] + bh[c + 4], 0.f);
            h0[c] = f2bf(v0); l0[c] = f2bf(v0 - bf2f(h0[c]));
            h1[c] = f2bf(v1); l1[c] = f2bf(v1 - bf2f(h1[c]));
        }
        size_t base = (size_t)(m0 + rg * 4 + r) * 256 + mode * 128 + cg2 * 8;
        *(s16x4*)&xhi[base] = h0;  *(s16x4*)&xhi[base + 4] = h1;
        *(s16x4*)&xlo[base] = l0;  *(s16x4*)&xlo[base + 4] = l1;
    }
}

// ---------------- merged weight packs: blocks [0,512)=wc, [512,640)=w1c, 640=bias ----------------
__global__ __launch_bounds__(256) void pack_all(const float* __restrict__ W1,
                                                const float* __restrict__ W_ih,
                                                const float* __restrict__ W_hh,
                                                const float* __restrict__ b_ih,
                                                const float* __restrict__ b_hh,
                                                short* __restrict__ w1chi,
                                                short* __restrict__ w1clo,
                                                short* __restrict__ wchi,
                                                short* __restrict__ wclo,
                                                float* __restrict__ bsum) {
    __shared__ float tile[32][33];
    const int b = blockIdx.x;
    if (b < 512) {
        // Wc gate-interleaved: packed row j <-> orig row (j&3)*256 + (j>>2)
        int idx = (b * 256 + threadIdx.x) * 4;
        int j = idx >> 9, k = idx & 511;
        int orig = (j & 3) * 256 + (j >> 2);
        const float* src = (k < 256) ? &W_ih[(size_t)orig * 256 + k]
                                     : &W_hh[(size_t)orig * 256 + (k - 256)];
        f32x4 v = *(const f32x4*)src;
        s16x4 hi, lo;
#pragma unroll
        for (int i = 0; i < 4; i++) {
            hi[i] = f2bf(v[i]);
            lo[i] = f2bf(v[i] - bf2f(hi[i]));
        }
        *(s16x4*)&wchi[idx] = hi;
        *(s16x4*)&wclo[idx] = lo;
    } else if (b < 640) {
        // W1 [512][256] -> Bc[j][k] hi/lo (transpose via LDS tile)
        const int bb = b - 512;
        const int k0 = (bb & 7) * 32;
        const int j0 = (bb >> 3) * 32;
        const int koff = (j0 >= 256) ? 256 : 0;
        const int joff = (j0 >= 256) ? 256 : 0;
        const int jj = threadIdx.x & 31, k4 = threadIdx.x >> 5;
#pragma unroll
        for (int s = 0; s < 4; s++) {
            int kk = k4 * 4 + s;
            tile[kk][jj] = W1[(size_t)(k0 + kk + koff) * 256 + (j0 + jj - joff)];
        }
        __syncthreads();
        const int kk2 = threadIdx.x & 31, j4 = threadIdx.x >> 5;
#pragma unroll
        for (int s = 0; s < 4; s++) {
            int j2 = j4 * 4 + s;
            float v = tile[kk2][j2];
            short hb = f2bf(v);
            w1chi[(size_t)(j0 + j2) * 256 + k0 + kk2] = hb;
            w1clo[(size_t)(j0 + j2) * 256 + k0 + kk2] = f2bf(v - bf2f(hb));
        }
    } else {
        // bsum gate-interleaved
#pragma unroll
        for (int s = 0; s < 4; s++) {
            int j = s * 256 + threadIdx.x;
            int orig = (j & 3) * 256 + (j >> 2);
            bsum[j] = b_ih[orig] + b_hh[orig];
        }
    }
}

// ---------------- cooperative LSTM: all 8 timesteps in one kernel ----------------
// 256 blocks x 512 thr, 1 block/CU (147 KB LDS). grid.sync() between steps.
// c lives in registers (each thread owns its fixed 8 channels). h via global dbuf.
// t=0 skips the K>=256 half (h==0), so h pair 0 is never read uninitialized.
__global__ __launch_bounds__(512) void lstm_seq(const short* __restrict__ xhi_all,
                                                const short* __restrict__ xlo_all,
                                                short* __restrict__ hhi0,
                                                short* __restrict__ hlo0,
                                                short* __restrict__ hhi1,
                                                short* __restrict__ hlo1,
                                                const short* __restrict__ wchi,
                                                const short* __restrict__ wclo,
                                                const float* __restrict__ bsum) {
    cg::grid_group gridg = cg::this_grid();
    __shared__ short Ah[2][128][40], Al[2][128][40];
    __shared__ short Bh[2][128][40], Bl[2][128][40];
    __shared__ float gl[128][132];
    const int m0 = blockIdx.x * 128;
    const int j0 = blockIdx.y * 128;
    const int tid = threadIdx.x;
    const int lane = tid & 63, wid = tid >> 6;
    const int wm = wid >> 2, wn = wid & 3;
    const int frow = lane & 15, kq = lane >> 4;
    const int sr = tid >> 2;
    const int sk8 = (tid & 3) * 8;

    // c in registers: thread owns rows (m0+erow), channels blockIdx.y*32 + ec0..+8
    const int erow = tid >> 2;
    const int ec0 = (tid & 3) * 8;
    const size_t cbase = (size_t)(m0 + erow) * 256 + blockIdx.y * 32 + ec0;
    f32x4 creg0 = {0.f, 0.f, 0.f, 0.f}, creg1 = {0.f, 0.f, 0.f, 0.f};

    // bias registers (constant across t)
    f32x4 bs[8];
#pragma unroll
    for (int i = 0; i < 8; i++)
        bs[i] = *(const f32x4*)&bsum[j0 + (ec0 + i) * 4];

    for (int t = 0; t < T_; t++) {
        const short* xhi = xhi_all + (size_t)t * N_ * 256;
        const short* xlo = xlo_all + (size_t)t * N_ * 256;
        const short* hr_hi = (t & 1) ? hhi1 : hhi0;
        const short* hr_lo = (t & 1) ? hlo1 : hlo0;
        short* hw_hi = (t & 1) ? hhi0 : hhi1;
        short* hw_lo = (t & 1) ? hlo0 : hlo1;
        const int nkt = (t == 0) ? 8 : 16;   // t=0: h==0, skip K>=256

        f32x4 acc[4][2];
        f32x4 zf = {0.f, 0.f, 0.f, 0.f};
#pragma unroll
        for (int m = 0; m < 4; m++)
#pragma unroll
            for (int n = 0; n < 2; n++) acc[m][n] = zf;

        s16x8 a_h, a_l, b_h, b_l;

        auto load_t = [&](int kt) {
            const int k0 = kt * 32;
            const short* ah = (k0 < 256) ? xhi : hr_hi;
            const short* al = (k0 < 256) ? xlo : hr_lo;
            const size_t abase = (size_t)(m0 + sr) * 256 + (k0 & 255) + sk8;
            a_h = *(const s16x8*)&ah[abase];
            a_l = *(const s16x8*)&al[abase];
            const size_t bb = (size_t)(j0 + sr) * 512 + k0 + sk8;
            b_h = *(const s16x8*)&wchi[bb];
            b_l = *(const s16x8*)&wclo[bb];
        };
        auto store_t = [&](int buf) {
            *(s16x8*)&Ah[buf][sr][sk8] = a_h;
            *(s16x8*)&Al[buf][sr][sk8] = a_l;
            *(s16x8*)&Bh[buf][sr][sk8] = b_h;
            *(s16x8*)&Bl[buf][sr][sk8] = b_l;
        };
        auto compute_t = [&](int buf) {
            s16x8 afh[4], afl[4], bfh[2], bfl[2];
#pragma unroll
            for (int m = 0; m < 4; m++) {
                afh[m] = *(const s16x8*)&Ah[buf][wm * 64 + m * 16 + frow][kq * 8];
                afl[m] = *(const s16x8*)&Al[buf][wm * 64 + m * 16 + frow][kq * 8];
            }
#pragma unroll
            for (int n = 0; n < 2; n++) {
                bfh[n] = *(const s16x8*)&Bh[buf][wn * 32 + n * 16 + frow][kq * 8];
                bfl[n] = *(const s16x8*)&Bl[buf][wn * 32 + n * 16 + frow][kq * 8];
            }
#pragma unroll
            for (int m = 0; m < 4; m++)
#pragma unroll
                for (int n = 0; n < 2; n++) {
                    acc[m][n] = __builtin_amdgcn_mfma_f32_16x16x32_bf16(afh[m], bfh[n], acc[m][n], 0, 0, 0);
                    acc[m][n] = __builtin_amdgcn_mfma_f32_16x16x32_bf16(afh[m], bfl[n], acc[m][n], 0, 0, 0);
                    acc[m][n] = __builtin_amdgcn_mfma_f32_16x16x32_bf16(afl[m], bfh[n], acc[m][n], 0, 0, 0);
                }
        };

        load_t(0);
        store_t(0);
        bar_nodrain();
#pragma unroll 2
        for (int kt = 0; kt < nkt; kt++) {
            const int cur = kt & 1;
            if (kt < nkt - 1) load_t(kt + 1);
            compute_t(cur);
            bar_nodrain();
            if (kt < nkt - 1) { store_t(cur ^ 1); bar_nodrain(); }
        }

        // epilogue: acc -> gl tile -> pointwise with register c
#pragma unroll
        for (int m = 0; m < 4; m++)
#pragma unroll
            for (int n = 0; n < 2; n++)
#pragma unroll
                for (int r = 0; r < 4; r++)
                    gl[wm * 64 + m * 16 + kq * 4 + r][wn * 32 + n * 16 + frow] = acc[m][n][r];
        bar_nodrain();

        s16x8 h8, l8;
#pragma unroll
        for (int i = 0; i < 8; i++) {
            f32x4 g4 = *(const f32x4*)&gl[erow][(ec0 + i) * 4];
            float si = 1.f / (1.f + expf(-(g4[0] + bs[i][0])));
            float sf = 1.f / (1.f + expf(-(g4[1] + bs[i][1])));
            float tg = tanhf(g4[2] + bs[i][2]);
            float so = 1.f / (1.f + expf(-(g4[3] + bs[i][3])));
            float cold = (i < 4) ? creg0[i] : creg1[i - 4];
            float cn = sf * cold + si * tg;
            float hv = so * tanhf(cn);
            if (i < 4) creg0[i] = cn; else creg1[i - 4] = cn;
            h8[i] = f2bf(hv);
            l8[i] = f2bf(hv - bf2f(h8[i]));
        }
        *(s16x8*)&hw_hi[cbase] = h8;
        *(s16x8*)&hw_lo[cbase] = l8;

        gridg.sync();   // h visible grid-wide; also block-local barrier for LDS reuse
    }
}

// ---------------- UV = h @ Bc^T  (M=4096, K=256, N=512) ----------------
__global__ __launch_bounds__(512) void uv_gemm(const short* __restrict__ hhi,
                                               const short* __restrict__ hlo,
                                               const short* __restrict__ whi,
                                               const short* __restrict__ wlo,
                                               float* __restrict__ UV) {
    __shared__ short Ah[2][128][40], Al[2][128][40];
    __shared__ short Bh[2][128][40], Bl[2][128][40];
    const int m0 = blockIdx.x * 128;
    const int j0 = blockIdx.y * 128;
    const int tid = threadIdx.x;
    const int lane = tid & 63, wid = tid >> 6;
    const int wm = wid >> 2, wn = wid & 3;
    const int frow = lane & 15, kq = lane >> 4;
    const int sr = tid >> 2;
    const int sk8 = (tid & 3) * 8;

    f32x4 acc[4][2];
    f32x4 zf = {0.f, 0.f, 0.f, 0.f};
#pragma unroll
    for (int m = 0; m < 4; m++)
#pragma unroll
        for (int n = 0; n < 2; n++) acc[m][n] = zf;

    s16x8 a_h, a_l, b_h, b_l;

    auto load_t = [&](int kt) {
        const int k0 = kt * 32;
        const size_t abase = (size_t)(m0 + sr) * 256 + k0 + sk8;
        a_h = *(const s16x8*)&hhi[abase];
        a_l = *(const s16x8*)&hlo[abase];
        const size_t bb = (size_t)(j0 + sr) * 256 + k0 + sk8;
        b_h = *(const s16x8*)&whi[bb];
        b_l = *(const s16x8*)&wlo[bb];
    };
    auto store_t = [&](int buf) {
        *(s16x8*)&Ah[buf][sr][sk8] = a_h;
        *(s16x8*)&Al[buf][sr][sk8] = a_l;
        *(s16x8*)&Bh[buf][sr][sk8] = b_h;
        *(s16x8*)&Bl[buf][sr][sk8] = b_l;
    };
    auto compute_t = [&](int buf) {
        s16x8 afh[4], afl[4], bfh[2], bfl[2];
#pragma unroll
        for (int m = 0; m < 4; m++) {
            afh[m] = *(const s16x8*)&Ah[buf][wm * 64 + m * 16 + frow][kq * 8];
            afl[m] = *(const s16x8*)&Al[buf][wm * 64 + m * 16 + frow][kq * 8];
        }
#pragma unroll
        for (int n = 0; n < 2; n++) {
            bfh[n] = *(const s16x8*)&Bh[buf][wn * 32 + n * 16 + frow][kq * 8];
            bfl[n] = *(const s16x8*)&Bl[buf][wn * 32 + n * 16 + frow][kq * 8];
        }
#pragma unroll
        for (int m = 0; m < 4; m++)
#pragma unroll
            for (int n = 0; n < 2; n++) {
                acc[m][n] = __builtin_amdgcn_mfma_f32_16x16x32_bf16(afh[m], bfh[n], acc[m][n], 0, 0, 0);
                acc[m][n] = __builtin_amdgcn_mfma_f32_16x16x32_bf16(afh[m], bfl[n], acc[m][n], 0, 0, 0);
                acc[m][n] = __builtin_amdgcn_mfma_f32_16x16x32_bf16(afl[m], bfh[n], acc[m][n], 0, 0, 0);
            }
    };

    load_t(0);
    store_t(0);
    bar_nodrain();
#pragma unroll 2
    for (int kt = 0; kt < 8; kt++) {
        const int cur = kt & 1;
        if (kt < 7) load_t(kt + 1);
        compute_t(cur);
        bar_nodrain();
        if (kt < 7) { store_t(cur ^ 1); bar_nodrain(); }
    }

#pragma unroll
    for (int m = 0; m < 4; m++)
#pragma unroll
        for (int n = 0; n < 2; n++)
#pragma unroll
            for (int r = 0; r < 4; r++) {
                int row = m0 + wm * 64 + m * 16 + kq * 4 + r;
                int col = j0 + wn * 32 + n * 16 + frow;
                UV[(size_t)row * 512 + col] = acc[m][n][r];
            }
}

// ---------------- per-edge: logit = relu(U[src]+V[dst]+b1) . W2 + b2 ----------------
__global__ __launch_bounds__(256) void mlp_edge(const float* __restrict__ UV,
                                                const int* __restrict__ eidx,
                                                const float* __restrict__ b1,
                                                const float* __restrict__ W2,
                                                const float* __restrict__ b2,
                                                float* __restrict__ out) {
    const int e = blockIdx.x * 4 + (threadIdx.x >> 6);
    const int lane = threadIdx.x & 63;
    const int c4 = lane * 4;
    const int src = eidx[e];
    const int dst = eidx[E_ + e];
    f32x4 u = *(const f32x4*)&UV[(size_t)src * 512 + c4];
    f32x4 v = *(const f32x4*)&UV[(size_t)dst * 512 + 256 + c4];
    f32x4 bb = *(const f32x4*)&b1[c4];
    f32x4 ww = *(const f32x4*)&W2[c4];
    float p = 0.f;
#pragma unroll
    for (int i = 0; i < 4; i++)
        p += fmaxf(u[i] + v[i] + bb[i], 0.f) * ww[i];
    p += __shfl_xor(p, 1);
    p += __shfl_xor(p, 2);
    p += __shfl_xor(p, 4);
    p += __shfl_xor(p, 8);
    p += __shfl_xor(p, 16);
    p += __shfl_xor(p, 32);
    if (lane == 0) out[e] = p + b2[0];
}

extern "C" void kernel_launch(void* const* d_in, const int* in_sizes, int n_in,
                              void* d_out, int out_size, void* d_ws, size_t ws_size,
                              hipStream_t stream) {
    (void)in_sizes; (void)n_in; (void)out_size; (void)ws_size;
    const float* feat  = (const float*)d_in[0];
    const float* P     = (const float*)d_in[1];
    const int*   eidx  = (const int*)d_in[2];
    const float* W_lpf = (const float*)d_in[3];
    const float* b_lpf = (const float*)d_in[4];
    const float* W_hpf = (const float*)d_in[5];
    const float* b_hpf = (const float*)d_in[6];
    const float* W_ih  = (const float*)d_in[7];
    const float* W_hh  = (const float*)d_in[8];
    const float* b_ih  = (const float*)d_in[9];
    const float* b_hh  = (const float*)d_in[10];
    const float* W1    = (const float*)d_in[11];
    const float* b1    = (const float*)d_in[12];
    const float* W2    = (const float*)d_in[13];
    const float* b2    = (const float*)d_in[14];
    float* out = (float*)d_out;

    // workspace layout (100.7 MB)
    char* ws = (char*)d_ws;
    float* xw    = (float*)ws;   ws += (size_t)T_ * N_ * 128 * 4;   // 16.78 MB (unused scratch)
    char*  ytreg = ws;           ws += (size_t)T_ * 256 * N_ * 2;   // 16.78 MB; yt then h dbuf
    char*  Zreg  = ws;           ws += (size_t)T_ * N_ * 256 * 4;   // 33.55 MB; PX then packs+UV
    short* xhi   = (short*)ws;   ws += (size_t)T_ * N_ * 256 * 2;   // 16.78 MB
    short* xlo   = (short*)ws;   ws += (size_t)T_ * N_ * 256 * 2;   // 16.78 MB
    (void)xw;

    short* yt    = (short*)ytreg;                 // 8.4 MB (T*128*N bf16), dead after pfy
    float* PX    = (float*)Zreg;                  // 16.8 MB, dead after hp2
    // ytreg after pfy: h double-buffer pairs (4 x 2 MB)
    short* hhi0  = (short*)ytreg;
    short* hlo0  = hhi0 + (size_t)N_ * 256;
    short* hhi1  = hlo0 + (size_t)N_ * 256;
    short* hlo1  = hhi1 + (size_t)N_ * 256;
    // Zreg after hp2_gemm: W packs + bias + UV
    short* w1chi = (short*)Zreg;
    short* w1clo = w1chi + (size_t)512 * 256;
    short* wchi  = w1clo + (size_t)512 * 256;
    short* wclo  = wchi + (size_t)1024 * 512;
    float* bsum  = (float*)(wclo + (size_t)1024 * 512);
    float* UV    = bsum + 1024;

    pack_yt<<<dim3(N_ / 32, 4, T_), 256, 0, stream>>>(feat, yt);
    pfy_gemm<<<dim3(N_ / 128, T_), 512, 0, stream>>>(P, yt, PX);
    hp2_gemm<<<dim3(T_ * N_ / 64, 2), 256, 0, stream>>>(feat, PX, W_lpf, W_hpf,
                                                        b_lpf, b_hpf, xhi, xlo);

    // PX dead from here — pack weights into Zreg (single merged kernel)
    pack_all<<<dim3(641), 256, 0, stream>>>(W1, W_ih, W_hh, b_ih, b_hh,
                                            w1chi, w1clo, wchi, wclo, bsum);

    // cooperative fused LSTM: 8 timesteps, grid-synced; c in registers;
    // t=0 skips the h half so h pair 0 needs no init. Final h -> pair 0.
    {
        const short* xh = xhi; const short* xl = xlo;
        void* args[] = { (void*)&xh, (void*)&xl,
                         (void*)&hhi0, (void*)&hlo0, (void*)&hhi1, (void*)&hlo1,
                         (void*)&wchi, (void*)&wclo, (void*)&bsum };
        hipLaunchCooperativeKernel(reinterpret_cast<void*>(lstm_seq),
                                   dim3(N_ / 128, 1024 / 128), dim3(512),
                                   args, 0, stream);
    }

    uv_gemm<<<dim3(N_ / 128, 512 / 128), 512, 0, stream>>>(hhi0, hlo0, w1chi, w1clo, UV);
    mlp_edge<<<dim3(E_ / 4), 256, 0, stream>>>(UV, eidx, b1, W2, b2, out);
}

// Round 18
// 395.701 us; speedup vs baseline: 1.6457x; 1.6457x over previous
//
#include <hip/hip_runtime.h>
#include <stdint.h>

#define T_ 8
#define N_ 4096
#define E_ 131072

typedef __attribute__((ext_vector_type(4))) float f32x4;
typedef __attribute__((ext_vector_type(8))) short s16x8;
typedef __attribute__((ext_vector_type(4))) short s16x4;

static __device__ __forceinline__ short f2bf(float f) {
    union { float f; unsigned u; } v; v.f = f;
    unsigned r = v.u + 0x7fffu + ((v.u >> 16) & 1u);   // RNE
    return (short)(r >> 16);
}
static __device__ __forceinline__ float bf2f(short s) {
    union { float f; unsigned u; } v; v.u = ((unsigned)(unsigned short)s) << 16;
    return v.f;
}

// barrier that does NOT drain vmcnt (validated round 14)
static __device__ __forceinline__ void bar_nodrain() {
    asm volatile("s_waitcnt lgkmcnt(0)\n\ts_barrier" ::: "memory");
}

// ---------------- Yt[t][j][n] (bf16) = X[t][n][j] transposed, j in [0,128) ----------------
__global__ __launch_bounds__(256) void pack_yt(const float* __restrict__ feat,
                                               short* __restrict__ yt) {
    __shared__ float tile[32][33];
    const int t = blockIdx.z, j0 = blockIdx.y * 32, n0 = blockIdx.x * 32;
    const float* src = feat + (size_t)t * N_ * 128 + j0;
    const int jj = threadIdx.x & 31, i4 = threadIdx.x >> 5;
#pragma unroll
    for (int s = 0; s < 4; s++) {
        int ii = i4 * 4 + s;
        tile[ii][jj] = src[(size_t)(n0 + ii) * 128 + jj];
    }
    __syncthreads();
    const int nn = threadIdx.x & 31, j4 = threadIdx.x >> 5;
#pragma unroll
    for (int s = 0; s < 4; s++) {
        int j2 = j4 * 4 + s;
        yt[(size_t)(t * 128 + j0 + j2) * N_ + n0 + nn] = f2bf(tile[nn][j2]);
    }
}

// ---------------- PX[t] = P[t] @ X[t]   (bf16 MFMA, fp32 acc; N=128) ----------------
__global__ __launch_bounds__(512) void pfy_gemm(const float* __restrict__ P,
                                                const short* __restrict__ Yt,
                                                float* __restrict__ Z) {
    __shared__ short As[2][128][72];   // [buf][row][k], 144B stride
    __shared__ short Bs[2][128][72];   // [buf][col][k]
    const int t = blockIdx.y;
    const int m0 = blockIdx.x * 128;
    const int tid = threadIdx.x;
    const int lane = tid & 63, wid = tid >> 6;
    const int wm = wid >> 2, wn = wid & 3;       // wave grid 2(M) x 4(N)
    const int frow = lane & 15, kq = lane >> 4;  // MFMA fragment coords

    const float* Pt = P + (size_t)t * N_ * N_;
    const short* Bt = Yt + (size_t)t * 128 * N_;

    const int ar = tid >> 2;           // A row 0..127
    const int ak16 = (tid & 3) * 16;   // k offset (floats)
    const int bj = tid >> 2;           // B row 0..127
    const int bk16 = (tid & 3) * 16;   // k offset (shorts)

    f32x4 acc[4][2];
    f32x4 zf = {0.f, 0.f, 0.f, 0.f};
#pragma unroll
    for (int m = 0; m < 4; m++)
#pragma unroll
        for (int n = 0; n < 2; n++) acc[m][n] = zf;

    f32x4 aA[4], aB[4]; s16x8 bA[2], bB[2];

    const float* Pr = &Pt[(size_t)(m0 + ar) * 4096 + ak16];
    const short* Br = &Bt[(size_t)bj * 4096 + bk16];

#define LOADA(KT) do { const int k0_ = (KT) * 64;                              \
        _Pragma("unroll") for (int i = 0; i < 4; i++)                          \
            aA[i] = *(const f32x4*)&Pr[k0_ + i * 4];                           \
        _Pragma("unroll") for (int i = 0; i < 2; i++)                          \
            bA[i] = *(const s16x8*)&Br[k0_ + i * 8]; } while (0)
#define LOADB(KT) do { const int k0_ = (KT) * 64;                              \
        _Pragma("unroll") for (int i = 0; i < 4; i++)                          \
            aB[i] = *(const f32x4*)&Pr[k0_ + i * 4];                           \
        _Pragma("unroll") for (int i = 0; i < 2; i++)                          \
            bB[i] = *(const s16x8*)&Br[k0_ + i * 8]; } while (0)
#define STOREA(BUF) do {                                                       \
        _Pragma("unroll") for (int i = 0; i < 4; i++) {                        \
            s16x4 c4_;                                                         \
            _Pragma("unroll") for (int j = 0; j < 4; j++) c4_[j] = f2bf(aA[i][j]); \
            *(s16x4*)&As[BUF][ar][ak16 + i * 4] = c4_; }                       \
        _Pragma("unroll") for (int i = 0; i < 2; i++)                          \
            *(s16x8*)&Bs[BUF][bj][bk16 + i * 8] = bA[i]; } while (0)
#define STOREB(BUF) do {                                                       \
        _Pragma("unroll") for (int i = 0; i < 4; i++) {                        \
            s16x4 c4_;                                                         \
            _Pragma("unroll") for (int j = 0; j < 4; j++) c4_[j] = f2bf(aB[i][j]); \
            *(s16x4*)&As[BUF][ar][ak16 + i * 4] = c4_; }                       \
        _Pragma("unroll") for (int i = 0; i < 2; i++)                          \
            *(s16x8*)&Bs[BUF][bj][bk16 + i * 8] = bB[i]; } while (0)

    auto compute_t = [&](int buf) {
#pragma unroll
        for (int ks = 0; ks < 2; ks++) {
            s16x8 af[4], bfr[2];
#pragma unroll
            for (int m = 0; m < 4; m++)
                af[m] = *(const s16x8*)&As[buf][wm * 64 + m * 16 + frow][kq * 8 + ks * 32];
#pragma unroll
            for (int n = 0; n < 2; n++)
                bfr[n] = *(const s16x8*)&Bs[buf][wn * 32 + n * 16 + frow][kq * 8 + ks * 32];
#pragma unroll
            for (int m = 0; m < 4; m++)
#pragma unroll
                for (int n = 0; n < 2; n++)
                    acc[m][n] = __builtin_amdgcn_mfma_f32_16x16x32_bf16(af[m], bfr[n], acc[m][n], 0, 0, 0);
        }
    };

    LOADA(0);
    STOREA(0);
    LOADB(1);
    LOADA(2);
    bar_nodrain();

#pragma unroll 2
    for (int kt = 0; kt < 64; kt++) {
        compute_t(kt & 1);
        if (kt < 63) {
            if ((kt & 1) == 0) {
                STOREB(1);
                if (kt + 3 < 64) LOADB(kt + 3);
            } else {
                STOREA(0);
                if (kt + 3 < 64) LOADA(kt + 3);
            }
            bar_nodrain();
        }
    }
#undef LOADA
#undef LOADB
#undef STOREA
#undef STOREB

    float* Zt = Z + (size_t)t * N_ * 128;
#pragma unroll
    for (int m = 0; m < 4; m++)
#pragma unroll
        for (int n = 0; n < 2; n++)
#pragma unroll
            for (int r = 0; r < 4; r++) {
                int row = m0 + wm * 64 + m * 16 + kq * 4 + r;  // C/D: row=(lane>>4)*4+reg
                int col = wn * 32 + n * 16 + frow;             //      col=lane&15
                Zt[(size_t)row * 128 + col] = acc[m][n][r];
            }
}

// ---------------- filter heads: mode 0: low = relu(PX@Wlp + b_lpf) -> xseq[:, :128]
//                  mode 1: high = relu((X-PX)@Whp + b_hpf) -> xseq[:, 128:]
__global__ __launch_bounds__(256) void hp2_gemm(const float* __restrict__ feat,
                                                const float* __restrict__ PX,
                                                const float* __restrict__ Wlp,
                                                const float* __restrict__ Whp,
                                                const float* __restrict__ b_lpf,
                                                const float* __restrict__ b_hpf,
                                                short* __restrict__ xhi,
                                                short* __restrict__ xlo) {
    __shared__ float As[32][68];
    __shared__ float Ws[32][132];
    const int m0 = blockIdx.x * 64;
    const int mode = blockIdx.y;            // 0 = low, 1 = high
    const float* W = mode ? Whp : Wlp;
    const float* bp = mode ? b_hpf : b_lpf;
    const int tid = threadIdx.x;
    const int rg = tid & 15, cg2 = tid >> 4;
    float acc[4][8];
#pragma unroll
    for (int r = 0; r < 4; r++)
#pragma unroll
        for (int c = 0; c < 8; c++) acc[r][c] = 0.f;

    for (int k0 = 0; k0 < 128; k0 += 32) {
#pragma unroll
        for (int s = 0; s < 2; s++) {
            int q = tid + s * 256, row = q >> 3, k4 = q & 7;
            f32x4 pv = *(const f32x4*)&PX[(size_t)(m0 + row) * 128 + k0 + k4 * 4];
            f32x4 v;
            if (mode) {
                f32x4 fv = *(const f32x4*)&feat[(size_t)(m0 + row) * 128 + k0 + k4 * 4];
#pragma unroll
                for (int i = 0; i < 4; i++) v[i] = fv[i] - pv[i];
            } else {
                v = pv;
            }
#pragma unroll
            for (int i = 0; i < 4; i++) As[k4 * 4 + i][row] = v[i];
        }
#pragma unroll
        for (int s = 0; s < 4; s++) {
            int q = tid + s * 256, kk = q >> 5, j4 = q & 31;
            *(f32x4*)&Ws[kk][j4 * 4] = *(const f32x4*)&W[(size_t)(k0 + kk) * 128 + j4 * 4];
        }
        __syncthreads();
#pragma unroll
        for (int kk = 0; kk < 32; kk++) {
            f32x4 a  = *(const f32x4*)&As[kk][rg * 4];
            f32x4 w0 = *(const f32x4*)&Ws[kk][cg2 * 8];
            f32x4 w1 = *(const f32x4*)&Ws[kk][cg2 * 8 + 4];
#pragma unroll
            for (int r = 0; r < 4; r++)
#pragma unroll
                for (int c = 0; c < 4; c++) {
                    acc[r][c]     += a[r] * w0[c];
                    acc[r][c + 4] += a[r] * w1[c];
                }
        }
        __syncthreads();
    }
    float bh[8];
#pragma unroll
    for (int c = 0; c < 8; c++) bh[c] = bp[cg2 * 8 + c];
#pragma unroll
    for (int r = 0; r < 4; r++) {
        s16x4 h0, h1, l0, l1;
#pragma unroll
        for (int c = 0; c < 4; c++) {
            float v0 = fmaxf(acc[r][c] + bh[c], 0.f);
            float v1 = fmaxf(acc[r][c + 4] + bh[c + 4], 0.f);
            h0[c] = f2bf(v0); l0[c] = f2bf(v0 - bf2f(h0[c]));
            h1[c] = f2bf(v1); l1[c] = f2bf(v1 - bf2f(h1[c]));
        }
        size_t base = (size_t)(m0 + rg * 4 + r) * 256 + mode * 128 + cg2 * 8;
        *(s16x4*)&xhi[base] = h0;  *(s16x4*)&xhi[base + 4] = h1;
        *(s16x4*)&xlo[base] = l0;  *(s16x4*)&xlo[base + 4] = l1;
    }
}

// ---------------- merged weight packs: blocks [0,512)=wc, [512,640)=w1c, 640=bias ----------------
__global__ __launch_bounds__(256) void pack_all(const float* __restrict__ W1,
                                                const float* __restrict__ W_ih,
                                                const float* __restrict__ W_hh,
                                                const float* __restrict__ b_ih,
                                                const float* __restrict__ b_hh,
                                                short* __restrict__ w1chi,
                                                short* __restrict__ w1clo,
                                                short* __restrict__ wchi,
                                                short* __restrict__ wclo,
                                                float* __restrict__ bsum) {
    __shared__ float tile[32][33];
    const int b = blockIdx.x;
    if (b < 512) {
        int idx = (b * 256 + threadIdx.x) * 4;
        int j = idx >> 9, k = idx & 511;
        int orig = (j & 3) * 256 + (j >> 2);
        const float* src = (k < 256) ? &W_ih[(size_t)orig * 256 + k]
                                     : &W_hh[(size_t)orig * 256 + (k - 256)];
        f32x4 v = *(const f32x4*)src;
        s16x4 hi, lo;
#pragma unroll
        for (int i = 0; i < 4; i++) {
            hi[i] = f2bf(v[i]);
            lo[i] = f2bf(v[i] - bf2f(hi[i]));
        }
        *(s16x4*)&wchi[idx] = hi;
        *(s16x4*)&wclo[idx] = lo;
    } else if (b < 640) {
        const int bb = b - 512;
        const int k0 = (bb & 7) * 32;
        const int j0 = (bb >> 3) * 32;
        const int koff = (j0 >= 256) ? 256 : 0;
        const int joff = (j0 >= 256) ? 256 : 0;
        const int jj = threadIdx.x & 31, k4 = threadIdx.x >> 5;
#pragma unroll
        for (int s = 0; s < 4; s++) {
            int kk = k4 * 4 + s;
            tile[kk][jj] = W1[(size_t)(k0 + kk + koff) * 256 + (j0 + jj - joff)];
        }
        __syncthreads();
        const int kk2 = threadIdx.x & 31, j4 = threadIdx.x >> 5;
#pragma unroll
        for (int s = 0; s < 4; s++) {
            int j2 = j4 * 4 + s;
            float v = tile[kk2][j2];
            short hb = f2bf(v);
            w1chi[(size_t)(j0 + j2) * 256 + k0 + kk2] = hb;
            w1clo[(size_t)(j0 + j2) * 256 + k0 + kk2] = f2bf(v - bf2f(hb));
        }
    } else {
#pragma unroll
        for (int s = 0; s < 4; s++) {
            int j = s * 256 + threadIdx.x;
            int orig = (j & 3) * 256 + (j >> 2);
            bsum[j] = b_ih[orig] + b_hh[orig];
        }
    }
}

// ---------------- fused LSTM step: gates GEMM + pointwise c/h ----------------
// nkt=8 for t=0 (h==0: skip K>=256 half, h buffers never read), else 16.
__global__ __launch_bounds__(512) void lstm_step(const short* __restrict__ xhi,
                                                 const short* __restrict__ xlo,
                                                 const short* __restrict__ hhi_r,
                                                 const short* __restrict__ hlo_r,
                                                 const short* __restrict__ wchi,
                                                 const short* __restrict__ wclo,
                                                 const float* __restrict__ bsum,
                                                 float* __restrict__ cbuf,
                                                 short* __restrict__ hhi_w,
                                                 short* __restrict__ hlo_w,
                                                 int nkt) {
    __shared__ short Ah[2][128][40], Al[2][128][40];
    __shared__ short Bh[2][128][40], Bl[2][128][40];
    __shared__ float gl[128][132];     // 16B-aligned row stride (528 B)
    const int m0 = blockIdx.x * 128;
    const int j0 = blockIdx.y * 128;
    const int tid = threadIdx.x;
    const int lane = tid & 63, wid = tid >> 6;
    const int wm = wid >> 2, wn = wid & 3;
    const int frow = lane & 15, kq = lane >> 4;

    const int sr = tid >> 2;
    const int sk8 = (tid & 3) * 8;

    f32x4 acc[4][2];
    f32x4 zf = {0.f, 0.f, 0.f, 0.f};
#pragma unroll
    for (int m = 0; m < 4; m++)
#pragma unroll
        for (int n = 0; n < 2; n++) acc[m][n] = zf;

    s16x8 a_h, a_l, b_h, b_l;

    auto load_t = [&](int kt) {
        const int k0 = kt * 32;
        const short* ah = (k0 < 256) ? xhi : hhi_r;
        const short* al = (k0 < 256) ? xlo : hlo_r;
        const size_t abase = (size_t)(m0 + sr) * 256 + (k0 & 255) + sk8;
        a_h = *(const s16x8*)&ah[abase];
        a_l = *(const s16x8*)&al[abase];
        const size_t bb = (size_t)(j0 + sr) * 512 + k0 + sk8;
        b_h = *(const s16x8*)&wchi[bb];
        b_l = *(const s16x8*)&wclo[bb];
    };
    auto store_t = [&](int buf) {
        *(s16x8*)&Ah[buf][sr][sk8] = a_h;
        *(s16x8*)&Al[buf][sr][sk8] = a_l;
        *(s16x8*)&Bh[buf][sr][sk8] = b_h;
        *(s16x8*)&Bl[buf][sr][sk8] = b_l;
    };
    auto compute_t = [&](int buf) {
        s16x8 afh[4], afl[4], bfh[2], bfl[2];
#pragma unroll
        for (int m = 0; m < 4; m++) {
            afh[m] = *(const s16x8*)&Ah[buf][wm * 64 + m * 16 + frow][kq * 8];
            afl[m] = *(const s16x8*)&Al[buf][wm * 64 + m * 16 + frow][kq * 8];
        }
#pragma unroll
        for (int n = 0; n < 2; n++) {
            bfh[n] = *(const s16x8*)&Bh[buf][wn * 32 + n * 16 + frow][kq * 8];
            bfl[n] = *(const s16x8*)&Bl[buf][wn * 32 + n * 16 + frow][kq * 8];
        }
#pragma unroll
        for (int m = 0; m < 4; m++)
#pragma unroll
            for (int n = 0; n < 2; n++) {
                acc[m][n] = __builtin_amdgcn_mfma_f32_16x16x32_bf16(afh[m], bfh[n], acc[m][n], 0, 0, 0);
                acc[m][n] = __builtin_amdgcn_mfma_f32_16x16x32_bf16(afh[m], bfl[n], acc[m][n], 0, 0, 0);
                acc[m][n] = __builtin_amdgcn_mfma_f32_16x16x32_bf16(afl[m], bfh[n], acc[m][n], 0, 0, 0);
            }
    };

    load_t(0);
    store_t(0);
    bar_nodrain();
#pragma unroll 2
    for (int kt = 0; kt < nkt; kt++) {
        const int cur = kt & 1;
        if (kt < nkt - 1) load_t(kt + 1);
        compute_t(cur);
        bar_nodrain();
        if (kt < nkt - 1) { store_t(cur ^ 1); bar_nodrain(); }
    }

    // epilogue: acc -> gl tile (distinct LDS array)
#pragma unroll
    for (int m = 0; m < 4; m++)
#pragma unroll
        for (int n = 0; n < 2; n++)
#pragma unroll
            for (int r = 0; r < 4; r++)
                gl[wm * 64 + m * 16 + kq * 4 + r][wn * 32 + n * 16 + frow] = acc[m][n][r];
    bar_nodrain();

    // pointwise: thread -> (row, 8 channels); gates i,f,g,o adjacent in packed cols
    const int erow = tid >> 2;
    const int ec0 = (tid & 3) * 8;
    const size_t cbase = (size_t)(m0 + erow) * 256 + blockIdx.y * 32 + ec0;
    f32x4 co0 = *(const f32x4*)&cbuf[cbase];
    f32x4 co1 = *(const f32x4*)&cbuf[cbase + 4];
    f32x4 cn0, cn1;
    s16x8 h8, l8;
#pragma unroll
    for (int i = 0; i < 8; i++) {
        f32x4 g4 = *(const f32x4*)&gl[erow][(ec0 + i) * 4];
        f32x4 bs = *(const f32x4*)&bsum[j0 + (ec0 + i) * 4];
        float si = 1.f / (1.f + expf(-(g4[0] + bs[0])));
        float sf = 1.f / (1.f + expf(-(g4[1] + bs[1])));
        float tg = tanhf(g4[2] + bs[2]);
        float so = 1.f / (1.f + expf(-(g4[3] + bs[3])));
        float cold = (i < 4) ? co0[i] : co1[i - 4];
        float cn = sf * cold + si * tg;
        float hv = so * tanhf(cn);
        if (i < 4) cn0[i] = cn; else cn1[i - 4] = cn;
        h8[i] = f2bf(hv);
        l8[i] = f2bf(hv - bf2f(h8[i]));
    }
    *(f32x4*)&cbuf[cbase] = cn0;
    *(f32x4*)&cbuf[cbase + 4] = cn1;
    *(s16x8*)&hhi_w[cbase] = h8;
    *(s16x8*)&hlo_w[cbase] = l8;
}

// ---------------- UV = h @ Bc^T  (M=4096, K=256, N=512) ----------------
__global__ __launch_bounds__(512) void uv_gemm(const short* __restrict__ hhi,
                                               const short* __restrict__ hlo,
                                               const short* __restrict__ whi,
                                               const short* __restrict__ wlo,
                                               float* __restrict__ UV) {
    __shared__ short Ah[2][128][40], Al[2][128][40];
    __shared__ short Bh[2][128][40], Bl[2][128][40];
    const int m0 = blockIdx.x * 128;
    const int j0 = blockIdx.y * 128;
    const int tid = threadIdx.x;
    const int lane = tid & 63, wid = tid >> 6;
    const int wm = wid >> 2, wn = wid & 3;
    const int frow = lane & 15, kq = lane >> 4;
    const int sr = tid >> 2;
    const int sk8 = (tid & 3) * 8;

    f32x4 acc[4][2];
    f32x4 zf = {0.f, 0.f, 0.f, 0.f};
#pragma unroll
    for (int m = 0; m < 4; m++)
#pragma unroll
        for (int n = 0; n < 2; n++) acc[m][n] = zf;

    s16x8 a_h, a_l, b_h, b_l;

    auto load_t = [&](int kt) {
        const int k0 = kt * 32;
        const size_t abase = (size_t)(m0 + sr) * 256 + k0 + sk8;
        a_h = *(const s16x8*)&hhi[abase];
        a_l = *(const s16x8*)&hlo[abase];
        const size_t bb = (size_t)(j0 + sr) * 256 + k0 + sk8;
        b_h = *(const s16x8*)&whi[bb];
        b_l = *(const s16x8*)&wlo[bb];
    };
    auto store_t = [&](int buf) {
        *(s16x8*)&Ah[buf][sr][sk8] = a_h;
        *(s16x8*)&Al[buf][sr][sk8] = a_l;
        *(s16x8*)&Bh[buf][sr][sk8] = b_h;
        *(s16x8*)&Bl[buf][sr][sk8] = b_l;
    };
    auto compute_t = [&](int buf) {
        s16x8 afh[4], afl[4], bfh[2], bfl[2];
#pragma unroll
        for (int m = 0; m < 4; m++) {
            afh[m] = *(const s16x8*)&Ah[buf][wm * 64 + m * 16 + frow][kq * 8];
            afl[m] = *(const s16x8*)&Al[buf][wm * 64 + m * 16 + frow][kq * 8];
        }
#pragma unroll
        for (int n = 0; n < 2; n++) {
            bfh[n] = *(const s16x8*)&Bh[buf][wn * 32 + n * 16 + frow][kq * 8];
            bfl[n] = *(const s16x8*)&Bl[buf][wn * 32 + n * 16 + frow][kq * 8];
        }
#pragma unroll
        for (int m = 0; m < 4; m++)
#pragma unroll
            for (int n = 0; n < 2; n++) {
                acc[m][n] = __builtin_amdgcn_mfma_f32_16x16x32_bf16(afh[m], bfh[n], acc[m][n], 0, 0, 0);
                acc[m][n] = __builtin_amdgcn_mfma_f32_16x16x32_bf16(afh[m], bfl[n], acc[m][n], 0, 0, 0);
                acc[m][n] = __builtin_amdgcn_mfma_f32_16x16x32_bf16(afl[m], bfh[n], acc[m][n], 0, 0, 0);
            }
    };

    load_t(0);
    store_t(0);
    bar_nodrain();
#pragma unroll 2
    for (int kt = 0; kt < 8; kt++) {
        const int cur = kt & 1;
        if (kt < 7) load_t(kt + 1);
        compute_t(cur);
        bar_nodrain();
        if (kt < 7) { store_t(cur ^ 1); bar_nodrain(); }
    }

#pragma unroll
    for (int m = 0; m < 4; m++)
#pragma unroll
        for (int n = 0; n < 2; n++)
#pragma unroll
            for (int r = 0; r < 4; r++) {
                int row = m0 + wm * 64 + m * 16 + kq * 4 + r;
                int col = j0 + wn * 32 + n * 16 + frow;
                UV[(size_t)row * 512 + col] = acc[m][n][r];
            }
}

// ---------------- per-edge: logit = relu(U[src]+V[dst]+b1) . W2 + b2 ----------------
__global__ __launch_bounds__(256) void mlp_edge(const float* __restrict__ UV,
                                                const int* __restrict__ eidx,
                                                const float* __restrict__ b1,
                                                const float* __restrict__ W2,
                                                const float* __restrict__ b2,
                                                float* __restrict__ out) {
    const int e = blockIdx.x * 4 + (threadIdx.x >> 6);
    const int lane = threadIdx.x & 63;
    const int c4 = lane * 4;
    const int src = eidx[e];
    const int dst = eidx[E_ + e];
    f32x4 u = *(const f32x4*)&UV[(size_t)src * 512 + c4];
    f32x4 v = *(const f32x4*)&UV[(size_t)dst * 512 + 256 + c4];
    f32x4 bb = *(const f32x4*)&b1[c4];
    f32x4 ww = *(const f32x4*)&W2[c4];
    float p = 0.f;
#pragma unroll
    for (int i = 0; i < 4; i++)
        p += fmaxf(u[i] + v[i] + bb[i], 0.f) * ww[i];
    p += __shfl_xor(p, 1);
    p += __shfl_xor(p, 2);
    p += __shfl_xor(p, 4);
    p += __shfl_xor(p, 8);
    p += __shfl_xor(p, 16);
    p += __shfl_xor(p, 32);
    if (lane == 0) out[e] = p + b2[0];
}

extern "C" void kernel_launch(void* const* d_in, const int* in_sizes, int n_in,
                              void* d_out, int out_size, void* d_ws, size_t ws_size,
                              hipStream_t stream) {
    (void)in_sizes; (void)n_in; (void)out_size; (void)ws_size;
    const float* feat  = (const float*)d_in[0];
    const float* P     = (const float*)d_in[1];
    const int*   eidx  = (const int*)d_in[2];
    const float* W_lpf = (const float*)d_in[3];
    const float* b_lpf = (const float*)d_in[4];
    const float* W_hpf = (const float*)d_in[5];
    const float* b_hpf = (const float*)d_in[6];
    const float* W_ih  = (const float*)d_in[7];
    const float* W_hh  = (const float*)d_in[8];
    const float* b_ih  = (const float*)d_in[9];
    const float* b_hh  = (const float*)d_in[10];
    const float* W1    = (const float*)d_in[11];
    const float* b1    = (const float*)d_in[12];
    const float* W2    = (const float*)d_in[13];
    const float* b2    = (const float*)d_in[14];
    float* out = (float*)d_out;

    // workspace layout (100.7 MB)
    char* ws = (char*)d_ws;
    float* xw    = (float*)ws;   ws += (size_t)T_ * N_ * 128 * 4;   // 16.78 MB (unused scratch)
    char*  ytreg = ws;           ws += (size_t)T_ * 256 * N_ * 2;   // 16.78 MB; yt then c + h dbuf
    char*  Zreg  = ws;           ws += (size_t)T_ * N_ * 256 * 4;   // 33.55 MB; PX then packs+UV
    short* xhi   = (short*)ws;   ws += (size_t)T_ * N_ * 256 * 2;   // 16.78 MB
    short* xlo   = (short*)ws;   ws += (size_t)T_ * N_ * 256 * 2;   // 16.78 MB
    (void)xw;

    short* yt    = (short*)ytreg;                 // 8.4 MB, dead after pfy
    float* PX    = (float*)Zreg;                  // 16.8 MB, dead after hp2
    // ytreg after pfy: c (4 MB) + h double-buffer pairs (4 x 2 MB)
    float* cbuf  = (float*)ytreg;
    short* hhi0  = (short*)(ytreg + (size_t)N_ * 256 * 4);
    short* hlo0  = hhi0 + (size_t)N_ * 256;
    short* hhi1  = hlo0 + (size_t)N_ * 256;
    short* hlo1  = hhi1 + (size_t)N_ * 256;
    // Zreg after hp2_gemm: W packs + bias + UV
    short* w1chi = (short*)Zreg;
    short* w1clo = w1chi + (size_t)512 * 256;
    short* wchi  = w1clo + (size_t)512 * 256;
    short* wclo  = wchi + (size_t)1024 * 512;
    float* bsum  = (float*)(wclo + (size_t)1024 * 512);
    float* UV    = bsum + 1024;

    pack_yt<<<dim3(N_ / 32, 4, T_), 256, 0, stream>>>(feat, yt);
    pfy_gemm<<<dim3(N_ / 128, T_), 512, 0, stream>>>(P, yt, PX);
    hp2_gemm<<<dim3(T_ * N_ / 64, 2), 256, 0, stream>>>(feat, PX, W_lpf, W_hpf,
                                                        b_lpf, b_hpf, xhi, xlo);

    // PX dead from here — pack weights into Zreg (single merged kernel)
    pack_all<<<dim3(641), 256, 0, stream>>>(W1, W_ih, W_hh, b_ih, b_hh,
                                            w1chi, w1clo, wchi, wclo, bsum);

    // zero c only (4 MB): t=0 skips the h half, so h pair 0 is written before read
    hipMemsetAsync(cbuf, 0, (size_t)N_ * 256 * 4, stream);

    for (int t = 0; t < T_; t++) {
        const short* hr_hi = (t & 1) ? hhi1 : hhi0;
        const short* hr_lo = (t & 1) ? hlo1 : hlo0;
        short* hw_hi = (t & 1) ? hhi0 : hhi1;
        short* hw_lo = (t & 1) ? hlo0 : hlo1;
        lstm_step<<<dim3(N_ / 128, 1024 / 128), 512, 0, stream>>>(
            xhi + (size_t)t * N_ * 256, xlo + (size_t)t * N_ * 256,
            hr_hi, hr_lo, wchi, wclo, bsum, cbuf, hw_hi, hw_lo,
            (t == 0) ? 8 : 16);
    }
    // t=7 (odd) wrote pair 0 -> final h is hhi0/hlo0

    uv_gemm<<<dim3(N_ / 128, 512 / 128), 512, 0, stream>>>(hhi0, hlo0, w1chi, w1clo, UV);
    mlp_edge<<<dim3(E_ / 4), 256, 0, stream>>>(UV, eidx, b1, W2, b2, out);
}

// Round 19
// 384.798 us; speedup vs baseline: 1.6923x; 1.0283x over previous
//
#include <hip/hip_runtime.h>
#include <stdint.h>

#define T_ 8
#define N_ 4096
#define E_ 131072

typedef __attribute__((ext_vector_type(4))) float f32x4;
typedef __attribute__((ext_vector_type(8))) short s16x8;
typedef __attribute__((ext_vector_type(4))) short s16x4;

static __device__ __forceinline__ short f2bf(float f) {
    union { float f; unsigned u; } v; v.f = f;
    unsigned r = v.u + 0x7fffu + ((v.u >> 16) & 1u);   // RNE
    return (short)(r >> 16);
}
static __device__ __forceinline__ float bf2f(short s) {
    union { float f; unsigned u; } v; v.u = ((unsigned)(unsigned short)s) << 16;
    return v.f;
}

// barrier that does NOT drain vmcnt (validated round 14)
static __device__ __forceinline__ void bar_nodrain() {
    asm volatile("s_waitcnt lgkmcnt(0)\n\ts_barrier" ::: "memory");
}

// ---------------- Yt[t][j][n] (bf16) = X[t][n][j] transposed, j in [0,128) ----------------
__global__ __launch_bounds__(256) void pack_yt(const float* __restrict__ feat,
                                               short* __restrict__ yt) {
    __shared__ float tile[32][33];
    const int t = blockIdx.z, j0 = blockIdx.y * 32, n0 = blockIdx.x * 32;
    const float* src = feat + (size_t)t * N_ * 128 + j0;
    const int jj = threadIdx.x & 31, i4 = threadIdx.x >> 5;
#pragma unroll
    for (int s = 0; s < 4; s++) {
        int ii = i4 * 4 + s;
        tile[ii][jj] = src[(size_t)(n0 + ii) * 128 + jj];
    }
    __syncthreads();
    const int nn = threadIdx.x & 31, j4 = threadIdx.x >> 5;
#pragma unroll
    for (int s = 0; s < 4; s++) {
        int j2 = j4 * 4 + s;
        yt[(size_t)(t * 128 + j0 + j2) * N_ + n0 + nn] = f2bf(tile[nn][j2]);
    }
}

// ---------------- PX[t] = P[t] @ X[t]   (bf16 MFMA, fp32 acc; N=128) ----------------
__global__ __launch_bounds__(512) void pfy_gemm(const float* __restrict__ P,
                                                const short* __restrict__ Yt,
                                                float* __restrict__ Z) {
    __shared__ short As[2][128][72];   // [buf][row][k], 144B stride
    __shared__ short Bs[2][128][72];   // [buf][col][k]
    const int t = blockIdx.y;
    const int m0 = blockIdx.x * 128;
    const int tid = threadIdx.x;
    const int lane = tid & 63, wid = tid >> 6;
    const int wm = wid >> 2, wn = wid & 3;       // wave grid 2(M) x 4(N)
    const int frow = lane & 15, kq = lane >> 4;  // MFMA fragment coords

    const float* Pt = P + (size_t)t * N_ * N_;
    const short* Bt = Yt + (size_t)t * 128 * N_;

    const int ar = tid >> 2;           // A row 0..127
    const int ak16 = (tid & 3) * 16;   // k offset (floats)
    const int bj = tid >> 2;           // B row 0..127
    const int bk16 = (tid & 3) * 16;   // k offset (shorts)

    f32x4 acc[4][2];
    f32x4 zf = {0.f, 0.f, 0.f, 0.f};
#pragma unroll
    for (int m = 0; m < 4; m++)
#pragma unroll
        for (int n = 0; n < 2; n++) acc[m][n] = zf;

    f32x4 aA[4], aB[4]; s16x8 bA[2], bB[2];

    const float* Pr = &Pt[(size_t)(m0 + ar) * 4096 + ak16];
    const short* Br = &Bt[(size_t)bj * 4096 + bk16];

#define LOADA(KT) do { const int k0_ = (KT) * 64;                              \
        _Pragma("unroll") for (int i = 0; i < 4; i++)                          \
            aA[i] = *(const f32x4*)&Pr[k0_ + i * 4];                           \
        _Pragma("unroll") for (int i = 0; i < 2; i++)                          \
            bA[i] = *(const s16x8*)&Br[k0_ + i * 8]; } while (0)
#define LOADB(KT) do { const int k0_ = (KT) * 64;                              \
        _Pragma("unroll") for (int i = 0; i < 4; i++)                          \
            aB[i] = *(const f32x4*)&Pr[k0_ + i * 4];                           \
        _Pragma("unroll") for (int i = 0; i < 2; i++)                          \
            bB[i] = *(const s16x8*)&Br[k0_ + i * 8]; } while (0)
#define STOREA(BUF) do {                                                       \
        _Pragma("unroll") for (int i = 0; i < 4; i++) {                        \
            s16x4 c4_;                                                         \
            _Pragma("unroll") for (int j = 0; j < 4; j++) c4_[j] = f2bf(aA[i][j]); \
            *(s16x4*)&As[BUF][ar][ak16 + i * 4] = c4_; }                       \
        _Pragma("unroll") for (int i = 0; i < 2; i++)                          \
            *(s16x8*)&Bs[BUF][bj][bk16 + i * 8] = bA[i]; } while (0)
#define STOREB(BUF) do {                                                       \
        _Pragma("unroll") for (int i = 0; i < 4; i++) {                        \
            s16x4 c4_;                                                         \
            _Pragma("unroll") for (int j = 0; j < 4; j++) c4_[j] = f2bf(aB[i][j]); \
            *(s16x4*)&As[BUF][ar][ak16 + i * 4] = c4_; }                       \
        _Pragma("unroll") for (int i = 0; i < 2; i++)                          \
            *(s16x8*)&Bs[BUF][bj][bk16 + i * 8] = bB[i]; } while (0)

    auto compute_t = [&](int buf) {
#pragma unroll
        for (int ks = 0; ks < 2; ks++) {
            s16x8 af[4], bfr[2];
#pragma unroll
            for (int m = 0; m < 4; m++)
                af[m] = *(const s16x8*)&As[buf][wm * 64 + m * 16 + frow][kq * 8 + ks * 32];
#pragma unroll
            for (int n = 0; n < 2; n++)
                bfr[n] = *(const s16x8*)&Bs[buf][wn * 32 + n * 16 + frow][kq * 8 + ks * 32];
#pragma unroll
            for (int m = 0; m < 4; m++)
#pragma unroll
                for (int n = 0; n < 2; n++)
                    acc[m][n] = __builtin_amdgcn_mfma_f32_16x16x32_bf16(af[m], bfr[n], acc[m][n], 0, 0, 0);
        }
    };

    LOADA(0);
    STOREA(0);
    LOADB(1);
    LOADA(2);
    bar_nodrain();

#pragma unroll 2
    for (int kt = 0; kt < 64; kt++) {
        compute_t(kt & 1);
        if (kt < 63) {
            if ((kt & 1) == 0) {
                STOREB(1);
                if (kt + 3 < 64) LOADB(kt + 3);
            } else {
                STOREA(0);
                if (kt + 3 < 64) LOADA(kt + 3);
            }
            bar_nodrain();
        }
    }
#undef LOADA
#undef LOADB
#undef STOREA
#undef STOREB

    float* Zt = Z + (size_t)t * N_ * 128;
#pragma unroll
    for (int m = 0; m < 4; m++)
#pragma unroll
        for (int n = 0; n < 2; n++)
#pragma unroll
            for (int r = 0; r < 4; r++) {
                int row = m0 + wm * 64 + m * 16 + kq * 4 + r;  // C/D: row=(lane>>4)*4+reg
                int col = wn * 32 + n * 16 + frow;             //      col=lane&15
                Zt[(size_t)row * 128 + col] = acc[m][n][r];
            }
}

// ---------------- MFMA filter heads (bf16 hi/lo, exact to ~2^-17) ----------------
// mode 0: low = relu(PX@Wlp + b_lpf) -> xseq[:, :128]
// mode 1: high = relu((X-PX)@Whp + b_hpf) -> xseq[:, 128:]
// B = wT[j][k] (pre-transposed hi/lo). BM=128, BN=128, BK=32, 4 kt iters.
__global__ __launch_bounds__(512) void hp2m(const float* __restrict__ feat,
                                            const float* __restrict__ PX,
                                            const short* __restrict__ wlpT_hi,
                                            const short* __restrict__ wlpT_lo,
                                            const short* __restrict__ whpT_hi,
                                            const short* __restrict__ whpT_lo,
                                            const float* __restrict__ b_lpf,
                                            const float* __restrict__ b_hpf,
                                            short* __restrict__ xhi,
                                            short* __restrict__ xlo) {
    __shared__ short Ah[2][128][40], Al[2][128][40];
    __shared__ short Bh[2][128][40], Bl[2][128][40];
    const int m0 = blockIdx.x * 128;
    const int mode = blockIdx.y;
    const short* wT_hi = mode ? whpT_hi : wlpT_hi;
    const short* wT_lo = mode ? whpT_lo : wlpT_lo;
    const float* bp = mode ? b_hpf : b_lpf;
    const int tid = threadIdx.x;
    const int lane = tid & 63, wid = tid >> 6;
    const int wm = wid >> 2, wn = wid & 3;
    const int frow = lane & 15, kq = lane >> 4;
    const int sr = tid >> 2;            // staging row 0..127
    const int sk8 = (tid & 3) * 8;      // k offset within 32

    f32x4 acc[4][2];
    f32x4 zf = {0.f, 0.f, 0.f, 0.f};
#pragma unroll
    for (int m = 0; m < 4; m++)
#pragma unroll
        for (int n = 0; n < 2; n++) acc[m][n] = zf;

    f32x4 v0, v1; s16x8 b_h, b_l;

    auto load_t = [&](int kt) {
        const int k0 = kt * 32;
        const size_t abase = (size_t)(m0 + sr) * 128 + k0 + sk8;
        v0 = *(const f32x4*)&PX[abase];
        v1 = *(const f32x4*)&PX[abase + 4];
        if (mode) {
            f32x4 f0 = *(const f32x4*)&feat[abase];
            f32x4 f1 = *(const f32x4*)&feat[abase + 4];
#pragma unroll
            for (int i = 0; i < 4; i++) { v0[i] = f0[i] - v0[i]; v1[i] = f1[i] - v1[i]; }
        }
        const size_t bb = (size_t)sr * 128 + k0 + sk8;
        b_h = *(const s16x8*)&wT_hi[bb];
        b_l = *(const s16x8*)&wT_lo[bb];
    };
    auto store_t = [&](int buf) {
        s16x8 hi8, lo8;
#pragma unroll
        for (int i = 0; i < 4; i++) {
            hi8[i] = f2bf(v0[i]);     lo8[i] = f2bf(v0[i] - bf2f(hi8[i]));
            hi8[i + 4] = f2bf(v1[i]); lo8[i + 4] = f2bf(v1[i] - bf2f(hi8[i + 4]));
        }
        *(s16x8*)&Ah[buf][sr][sk8] = hi8;
        *(s16x8*)&Al[buf][sr][sk8] = lo8;
        *(s16x8*)&Bh[buf][sr][sk8] = b_h;
        *(s16x8*)&Bl[buf][sr][sk8] = b_l;
    };
    auto compute_t = [&](int buf) {
        s16x8 afh[4], afl[4], bfh[2], bfl[2];
#pragma unroll
        for (int m = 0; m < 4; m++) {
            afh[m] = *(const s16x8*)&Ah[buf][wm * 64 + m * 16 + frow][kq * 8];
            afl[m] = *(const s16x8*)&Al[buf][wm * 64 + m * 16 + frow][kq * 8];
        }
#pragma unroll
        for (int n = 0; n < 2; n++) {
            bfh[n] = *(const s16x8*)&Bh[buf][wn * 32 + n * 16 + frow][kq * 8];
            bfl[n] = *(const s16x8*)&Bl[buf][wn * 32 + n * 16 + frow][kq * 8];
        }
#pragma unroll
        for (int m = 0; m < 4; m++)
#pragma unroll
            for (int n = 0; n < 2; n++) {
                acc[m][n] = __builtin_amdgcn_mfma_f32_16x16x32_bf16(afh[m], bfh[n], acc[m][n], 0, 0, 0);
                acc[m][n] = __builtin_amdgcn_mfma_f32_16x16x32_bf16(afh[m], bfl[n], acc[m][n], 0, 0, 0);
                acc[m][n] = __builtin_amdgcn_mfma_f32_16x16x32_bf16(afl[m], bfh[n], acc[m][n], 0, 0, 0);
            }
    };

    load_t(0);
    store_t(0);
    bar_nodrain();
#pragma unroll
    for (int kt = 0; kt < 4; kt++) {
        const int cur = kt & 1;
        if (kt < 3) load_t(kt + 1);
        compute_t(cur);
        bar_nodrain();
        if (kt < 3) { store_t(cur ^ 1); bar_nodrain(); }
    }

    // epilogue: bias + relu + hi/lo split, C/D layout mapping
    float bv[2];
#pragma unroll
    for (int n = 0; n < 2; n++) bv[n] = bp[wn * 32 + n * 16 + frow];
#pragma unroll
    for (int m = 0; m < 4; m++)
#pragma unroll
        for (int n = 0; n < 2; n++)
#pragma unroll
            for (int r = 0; r < 4; r++) {
                int row = m0 + wm * 64 + m * 16 + kq * 4 + r;
                int col = wn * 32 + n * 16 + frow;
                float val = fmaxf(acc[m][n][r] + bv[n], 0.f);
                short hb = f2bf(val);
                size_t o = (size_t)row * 256 + mode * 128 + col;
                xhi[o] = hb;
                xlo[o] = f2bf(val - bf2f(hb));
            }
}

// ---------------- merged packs: [0,512)=wc, [512,640)=w1c, 640=bias, [641,673)=wT ----------------
__global__ __launch_bounds__(256) void pack_all(const float* __restrict__ W1,
                                                const float* __restrict__ W_ih,
                                                const float* __restrict__ W_hh,
                                                const float* __restrict__ b_ih,
                                                const float* __restrict__ b_hh,
                                                const float* __restrict__ W_lpf,
                                                const float* __restrict__ W_hpf,
                                                short* __restrict__ w1chi,
                                                short* __restrict__ w1clo,
                                                short* __restrict__ wchi,
                                                short* __restrict__ wclo,
                                                float* __restrict__ bsum,
                                                short* __restrict__ wlpT_hi,
                                                short* __restrict__ wlpT_lo,
                                                short* __restrict__ whpT_hi,
                                                short* __restrict__ whpT_lo) {
    __shared__ float tile[32][33];
    const int b = blockIdx.x;
    if (b < 512) {
        int idx = (b * 256 + threadIdx.x) * 4;
        int j = idx >> 9, k = idx & 511;
        int orig = (j & 3) * 256 + (j >> 2);
        const float* src = (k < 256) ? &W_ih[(size_t)orig * 256 + k]
                                     : &W_hh[(size_t)orig * 256 + (k - 256)];
        f32x4 v = *(const f32x4*)src;
        s16x4 hi, lo;
#pragma unroll
        for (int i = 0; i < 4; i++) {
            hi[i] = f2bf(v[i]);
            lo[i] = f2bf(v[i] - bf2f(hi[i]));
        }
        *(s16x4*)&wchi[idx] = hi;
        *(s16x4*)&wclo[idx] = lo;
    } else if (b < 640) {
        const int bb = b - 512;
        const int k0 = (bb & 7) * 32;
        const int j0 = (bb >> 3) * 32;
        const int koff = (j0 >= 256) ? 256 : 0;
        const int joff = (j0 >= 256) ? 256 : 0;
        const int jj = threadIdx.x & 31, k4 = threadIdx.x >> 5;
#pragma unroll
        for (int s = 0; s < 4; s++) {
            int kk = k4 * 4 + s;
            tile[kk][jj] = W1[(size_t)(k0 + kk + koff) * 256 + (j0 + jj - joff)];
        }
        __syncthreads();
        const int kk2 = threadIdx.x & 31, j4 = threadIdx.x >> 5;
#pragma unroll
        for (int s = 0; s < 4; s++) {
            int j2 = j4 * 4 + s;
            float v = tile[kk2][j2];
            short hb = f2bf(v);
            w1chi[(size_t)(j0 + j2) * 256 + k0 + kk2] = hb;
            w1clo[(size_t)(j0 + j2) * 256 + k0 + kk2] = f2bf(v - bf2f(hb));
        }
    } else if (b == 640) {
#pragma unroll
        for (int s = 0; s < 4; s++) {
            int j = s * 256 + threadIdx.x;
            int orig = (j & 3) * 256 + (j >> 2);
            bsum[j] = b_ih[orig] + b_hh[orig];
        }
    } else {
        // wT packs: W[k][j] (128x128) -> wT[j][k] hi/lo
        const int bb2 = b - 641;
        const int wsel = bb2 >> 4;
        const int t16 = bb2 & 15;
        const int k0 = (t16 & 3) * 32;
        const int j0 = (t16 >> 2) * 32;
        const float* Wsrc = wsel ? W_hpf : W_lpf;
        short* dhi = wsel ? whpT_hi : wlpT_hi;
        short* dlo = wsel ? whpT_lo : wlpT_lo;
        const int jj = threadIdx.x & 31, k4 = threadIdx.x >> 5;
#pragma unroll
        for (int s = 0; s < 4; s++) {
            int kk = k4 * 4 + s;
            tile[kk][jj] = Wsrc[(size_t)(k0 + kk) * 128 + (j0 + jj)];
        }
        __syncthreads();
        const int kk2 = threadIdx.x & 31, j4 = threadIdx.x >> 5;
#pragma unroll
        for (int s = 0; s < 4; s++) {
            int j2 = j4 * 4 + s;
            float v = tile[kk2][j2];
            short hb = f2bf(v);
            dhi[(size_t)(j0 + j2) * 128 + k0 + kk2] = hb;
            dlo[(size_t)(j0 + j2) * 128 + k0 + kk2] = f2bf(v - bf2f(hb));
        }
    }
}

// ---------------- fused LSTM step: gates GEMM + pointwise c/h ----------------
// nkt=8 & czero for t=0 (h==0, c==0: skip K>=256 half and cbuf read).
__global__ __launch_bounds__(512) void lstm_step(const short* __restrict__ xhi,
                                                 const short* __restrict__ xlo,
                                                 const short* __restrict__ hhi_r,
                                                 const short* __restrict__ hlo_r,
                                                 const short* __restrict__ wchi,
                                                 const short* __restrict__ wclo,
                                                 const float* __restrict__ bsum,
                                                 float* __restrict__ cbuf,
                                                 short* __restrict__ hhi_w,
                                                 short* __restrict__ hlo_w,
                                                 int nkt, int czero) {
    __shared__ short Ah[2][128][40], Al[2][128][40];
    __shared__ short Bh[2][128][40], Bl[2][128][40];
    __shared__ float gl[128][132];     // 16B-aligned row stride (528 B)
    const int m0 = blockIdx.x * 128;
    const int j0 = blockIdx.y * 128;
    const int tid = threadIdx.x;
    const int lane = tid & 63, wid = tid >> 6;
    const int wm = wid >> 2, wn = wid & 3;
    const int frow = lane & 15, kq = lane >> 4;

    const int sr = tid >> 2;
    const int sk8 = (tid & 3) * 8;

    f32x4 acc[4][2];
    f32x4 zf = {0.f, 0.f, 0.f, 0.f};
#pragma unroll
    for (int m = 0; m < 4; m++)
#pragma unroll
        for (int n = 0; n < 2; n++) acc[m][n] = zf;

    s16x8 a_h, a_l, b_h, b_l;

    auto load_t = [&](int kt) {
        const int k0 = kt * 32;
        const short* ah = (k0 < 256) ? xhi : hhi_r;
        const short* al = (k0 < 256) ? xlo : hlo_r;
        const size_t abase = (size_t)(m0 + sr) * 256 + (k0 & 255) + sk8;
        a_h = *(const s16x8*)&ah[abase];
        a_l = *(const s16x8*)&al[abase];
        const size_t bb = (size_t)(j0 + sr) * 512 + k0 + sk8;
        b_h = *(const s16x8*)&wchi[bb];
        b_l = *(const s16x8*)&wclo[bb];
    };
    auto store_t = [&](int buf) {
        *(s16x8*)&Ah[buf][sr][sk8] = a_h;
        *(s16x8*)&Al[buf][sr][sk8] = a_l;
        *(s16x8*)&Bh[buf][sr][sk8] = b_h;
        *(s16x8*)&Bl[buf][sr][sk8] = b_l;
    };
    auto compute_t = [&](int buf) {
        s16x8 afh[4], afl[4], bfh[2], bfl[2];
#pragma unroll
        for (int m = 0; m < 4; m++) {
            afh[m] = *(const s16x8*)&Ah[buf][wm * 64 + m * 16 + frow][kq * 8];
            afl[m] = *(const s16x8*)&Al[buf][wm * 64 + m * 16 + frow][kq * 8];
        }
#pragma unroll
        for (int n = 0; n < 2; n++) {
            bfh[n] = *(const s16x8*)&Bh[buf][wn * 32 + n * 16 + frow][kq * 8];
            bfl[n] = *(const s16x8*)&Bl[buf][wn * 32 + n * 16 + frow][kq * 8];
        }
#pragma unroll
        for (int m = 0; m < 4; m++)
#pragma unroll
            for (int n = 0; n < 2; n++) {
                acc[m][n] = __builtin_amdgcn_mfma_f32_16x16x32_bf16(afh[m], bfh[n], acc[m][n], 0, 0, 0);
                acc[m][n] = __builtin_amdgcn_mfma_f32_16x16x32_bf16(afh[m], bfl[n], acc[m][n], 0, 0, 0);
                acc[m][n] = __builtin_amdgcn_mfma_f32_16x16x32_bf16(afl[m], bfh[n], acc[m][n], 0, 0, 0);
            }
    };

    load_t(0);
    store_t(0);
    bar_nodrain();
#pragma unroll 2
    for (int kt = 0; kt < nkt; kt++) {
        const int cur = kt & 1;
        if (kt < nkt - 1) load_t(kt + 1);
        compute_t(cur);
        bar_nodrain();
        if (kt < nkt - 1) { store_t(cur ^ 1); bar_nodrain(); }
    }

    // epilogue: acc -> gl tile (distinct LDS array)
#pragma unroll
    for (int m = 0; m < 4; m++)
#pragma unroll
        for (int n = 0; n < 2; n++)
#pragma unroll
            for (int r = 0; r < 4; r++)
                gl[wm * 64 + m * 16 + kq * 4 + r][wn * 32 + n * 16 + frow] = acc[m][n][r];
    bar_nodrain();

    // pointwise: thread -> (row, 8 channels); gates i,f,g,o adjacent in packed cols
    const int erow = tid >> 2;
    const int ec0 = (tid & 3) * 8;
    const size_t cbase = (size_t)(m0 + erow) * 256 + blockIdx.y * 32 + ec0;
    f32x4 co0 = {0.f, 0.f, 0.f, 0.f}, co1 = {0.f, 0.f, 0.f, 0.f};
    if (!czero) {
        co0 = *(const f32x4*)&cbuf[cbase];
        co1 = *(const f32x4*)&cbuf[cbase + 4];
    }
    f32x4 cn0, cn1;
    s16x8 h8, l8;
#pragma unroll
    for (int i = 0; i < 8; i++) {
        f32x4 g4 = *(const f32x4*)&gl[erow][(ec0 + i) * 4];
        f32x4 bs = *(const f32x4*)&bsum[j0 + (ec0 + i) * 4];
        float si = 1.f / (1.f + expf(-(g4[0] + bs[0])));
        float sf = 1.f / (1.f + expf(-(g4[1] + bs[1])));
        float tg = tanhf(g4[2] + bs[2]);
        float so = 1.f / (1.f + expf(-(g4[3] + bs[3])));
        float cold = (i < 4) ? co0[i] : co1[i - 4];
        float cn = sf * cold + si * tg;
        float hv = so * tanhf(cn);
        if (i < 4) cn0[i] = cn; else cn1[i - 4] = cn;
        h8[i] = f2bf(hv);
        l8[i] = f2bf(hv - bf2f(h8[i]));
    }
    *(f32x4*)&cbuf[cbase] = cn0;
    *(f32x4*)&cbuf[cbase + 4] = cn1;
    *(s16x8*)&hhi_w[cbase] = h8;
    *(s16x8*)&hlo_w[cbase] = l8;
}

// ---------------- UV = h @ Bc^T  (M=4096, K=256, N=512) ----------------
__global__ __launch_bounds__(512) void uv_gemm(const short* __restrict__ hhi,
                                               const short* __restrict__ hlo,
                                               const short* __restrict__ whi,
                                               const short* __restrict__ wlo,
                                               float* __restrict__ UV) {
    __shared__ short Ah[2][128][40], Al[2][128][40];
    __shared__ short Bh[2][128][40], Bl[2][128][40];
    const int m0 = blockIdx.x * 128;
    const int j0 = blockIdx.y * 128;
    const int tid = threadIdx.x;
    const int lane = tid & 63, wid = tid >> 6;
    const int wm = wid >> 2, wn = wid & 3;
    const int frow = lane & 15, kq = lane >> 4;
    const int sr = tid >> 2;
    const int sk8 = (tid & 3) * 8;

    f32x4 acc[4][2];
    f32x4 zf = {0.f, 0.f, 0.f, 0.f};
#pragma unroll
    for (int m = 0; m < 4; m++)
#pragma unroll
        for (int n = 0; n < 2; n++) acc[m][n] = zf;

    s16x8 a_h, a_l, b_h, b_l;

    auto load_t = [&](int kt) {
        const int k0 = kt * 32;
        const size_t abase = (size_t)(m0 + sr) * 256 + k0 + sk8;
        a_h = *(const s16x8*)&hhi[abase];
        a_l = *(const s16x8*)&hlo[abase];
        const size_t bb = (size_t)(j0 + sr) * 256 + k0 + sk8;
        b_h = *(const s16x8*)&whi[bb];
        b_l = *(const s16x8*)&wlo[bb];
    };
    auto store_t = [&](int buf) {
        *(s16x8*)&Ah[buf][sr][sk8] = a_h;
        *(s16x8*)&Al[buf][sr][sk8] = a_l;
        *(s16x8*)&Bh[buf][sr][sk8] = b_h;
        *(s16x8*)&Bl[buf][sr][sk8] = b_l;
    };
    auto compute_t = [&](int buf) {
        s16x8 afh[4], afl[4], bfh[2], bfl[2];
#pragma unroll
        for (int m = 0; m < 4; m++) {
            afh[m] = *(const s16x8*)&Ah[buf][wm * 64 + m * 16 + frow][kq * 8];
            afl[m] = *(const s16x8*)&Al[buf][wm * 64 + m * 16 + frow][kq * 8];
        }
#pragma unroll
        for (int n = 0; n < 2; n++) {
            bfh[n] = *(const s16x8*)&Bh[buf][wn * 32 + n * 16 + frow][kq * 8];
            bfl[n] = *(const s16x8*)&Bl[buf][wn * 32 + n * 16 + frow][kq * 8];
        }
#pragma unroll
        for (int m = 0; m < 4; m++)
#pragma unroll
            for (int n = 0; n < 2; n++) {
                acc[m][n] = __builtin_amdgcn_mfma_f32_16x16x32_bf16(afh[m], bfh[n], acc[m][n], 0, 0, 0);
                acc[m][n] = __builtin_amdgcn_mfma_f32_16x16x32_bf16(afh[m], bfl[n], acc[m][n], 0, 0, 0);
                acc[m][n] = __builtin_amdgcn_mfma_f32_16x16x32_bf16(afl[m], bfh[n], acc[m][n], 0, 0, 0);
            }
    };

    load_t(0);
    store_t(0);
    bar_nodrain();
#pragma unroll 2
    for (int kt = 0; kt < 8; kt++) {
        const int cur = kt & 1;
        if (kt < 7) load_t(kt + 1);
        compute_t(cur);
        bar_nodrain();
        if (kt < 7) { store_t(cur ^ 1); bar_nodrain(); }
    }

#pragma unroll
    for (int m = 0; m < 4; m++)
#pragma unroll
        for (int n = 0; n < 2; n++)
#pragma unroll
            for (int r = 0; r < 4; r++) {
                int row = m0 + wm * 64 + m * 16 + kq * 4 + r;
                int col = j0 + wn * 32 + n * 16 + frow;
                UV[(size_t)row * 512 + col] = acc[m][n][r];
            }
}

// ---------------- per-edge: logit = relu(U[src]+V[dst]+b1) . W2 + b2 ----------------
__global__ __launch_bounds__(256) void mlp_edge(const float* __restrict__ UV,
                                                const int* __restrict__ eidx,
                                                const float* __restrict__ b1,
                                                const float* __restrict__ W2,
                                                const float* __restrict__ b2,
                                                float* __restrict__ out) {
    const int e = blockIdx.x * 4 + (threadIdx.x >> 6);
    const int lane = threadIdx.x & 63;
    const int c4 = lane * 4;
    const int src = eidx[e];
    const int dst = eidx[E_ + e];
    f32x4 u = *(const f32x4*)&UV[(size_t)src * 512 + c4];
    f32x4 v = *(const f32x4*)&UV[(size_t)dst * 512 + 256 + c4];
    f32x4 bb = *(const f32x4*)&b1[c4];
    f32x4 ww = *(const f32x4*)&W2[c4];
    float p = 0.f;
#pragma unroll
    for (int i = 0; i < 4; i++)
        p += fmaxf(u[i] + v[i] + bb[i], 0.f) * ww[i];
    p += __shfl_xor(p, 1);
    p += __shfl_xor(p, 2);
    p += __shfl_xor(p, 4);
    p += __shfl_xor(p, 8);
    p += __shfl_xor(p, 16);
    p += __shfl_xor(p, 32);
    if (lane == 0) out[e] = p + b2[0];
}

extern "C" void kernel_launch(void* const* d_in, const int* in_sizes, int n_in,
                              void* d_out, int out_size, void* d_ws, size_t ws_size,
                              hipStream_t stream) {
    (void)in_sizes; (void)n_in; (void)out_size; (void)ws_size;
    const float* feat  = (const float*)d_in[0];
    const float* P     = (const float*)d_in[1];
    const int*   eidx  = (const int*)d_in[2];
    const float* W_lpf = (const float*)d_in[3];
    const float* b_lpf = (const float*)d_in[4];
    const float* W_hpf = (const float*)d_in[5];
    const float* b_hpf = (const float*)d_in[6];
    const float* W_ih  = (const float*)d_in[7];
    const float* W_hh  = (const float*)d_in[8];
    const float* b_ih  = (const float*)d_in[9];
    const float* b_hh  = (const float*)d_in[10];
    const float* W1    = (const float*)d_in[11];
    const float* b1    = (const float*)d_in[12];
    const float* W2    = (const float*)d_in[13];
    const float* b2    = (const float*)d_in[14];
    float* out = (float*)d_out;

    // workspace layout (100.7 MB)
    char* ws = (char*)d_ws;
    char*  pkreg = ws;           ws += (size_t)T_ * N_ * 128 * 4;   // 16.78 MB: weight packs
    char*  ytreg = ws;           ws += (size_t)T_ * 256 * N_ * 2;   // 16.78 MB; yt then c + h dbuf
    char*  Zreg  = ws;           ws += (size_t)T_ * N_ * 256 * 4;   // 33.55 MB; PX then UV
    short* xhi   = (short*)ws;   ws += (size_t)T_ * N_ * 256 * 2;   // 16.78 MB
    short* xlo   = (short*)ws;   ws += (size_t)T_ * N_ * 256 * 2;   // 16.78 MB

    // packs in pkreg (built first, independent of PX)
    short* w1chi = (short*)pkreg;
    short* w1clo = w1chi + (size_t)512 * 256;
    short* wchi  = w1clo + (size_t)512 * 256;
    short* wclo  = wchi + (size_t)1024 * 512;
    float* bsum  = (float*)(wclo + (size_t)1024 * 512);
    short* wlpT_hi = (short*)(bsum + 1024);
    short* wlpT_lo = wlpT_hi + 128 * 128;
    short* whpT_hi = wlpT_lo + 128 * 128;
    short* whpT_lo = whpT_hi + 128 * 128;

    short* yt    = (short*)ytreg;                 // 8.4 MB, dead after pfy
    float* PX    = (float*)Zreg;                  // 16.8 MB, dead after hp2m
    // ytreg after pfy: c (4 MB) + h double-buffer pairs (4 x 2 MB)
    float* cbuf  = (float*)ytreg;
    short* hhi0  = (short*)(ytreg + (size_t)N_ * 256 * 4);
    short* hlo0  = hhi0 + (size_t)N_ * 256;
    short* hhi1  = hlo0 + (size_t)N_ * 256;
    short* hlo1  = hhi1 + (size_t)N_ * 256;
    float* UV    = (float*)Zreg;                  // reuse Zreg after PX dead

    pack_all<<<dim3(673), 256, 0, stream>>>(W1, W_ih, W_hh, b_ih, b_hh, W_lpf, W_hpf,
                                            w1chi, w1clo, wchi, wclo, bsum,
                                            wlpT_hi, wlpT_lo, whpT_hi, whpT_lo);
    pack_yt<<<dim3(N_ / 32, 4, T_), 256, 0, stream>>>(feat, yt);
    pfy_gemm<<<dim3(N_ / 128, T_), 512, 0, stream>>>(P, yt, PX);
    hp2m<<<dim3(T_ * N_ / 128, 2), 512, 0, stream>>>(feat, PX, wlpT_hi, wlpT_lo,
                                                     whpT_hi, whpT_lo, b_lpf, b_hpf,
                                                     xhi, xlo);

    for (int t = 0; t < T_; t++) {
        const short* hr_hi = (t & 1) ? hhi1 : hhi0;
        const short* hr_lo = (t & 1) ? hlo1 : hlo0;
        short* hw_hi = (t & 1) ? hhi0 : hhi1;
        short* hw_lo = (t & 1) ? hlo0 : hlo1;
        lstm_step<<<dim3(N_ / 128, 1024 / 128), 512, 0, stream>>>(
            xhi + (size_t)t * N_ * 256, xlo + (size_t)t * N_ * 256,
            hr_hi, hr_lo, wchi, wclo, bsum, cbuf, hw_hi, hw_lo,
            (t == 0) ? 8 : 16, (t == 0) ? 1 : 0);
    }
    // t=7 (odd) wrote pair 0 -> final h is hhi0/hlo0

    uv_gemm<<<dim3(N_ / 128, 512 / 128), 512, 0, stream>>>(hhi0, hlo0, w1chi, w1clo, UV);
    mlp_edge<<<dim3(E_ / 4), 256, 0, stream>>>(UV, eidx, b1, W2, b2, out);
}

// Round 20
// 349.341 us; speedup vs baseline: 1.8641x; 1.1015x over previous
//
#include <hip/hip_runtime.h>
#include <stdint.h>

#define T_ 8
#define N_ 4096
#define E_ 131072

typedef __attribute__((ext_vector_type(4))) float f32x4;
typedef __attribute__((ext_vector_type(8))) short s16x8;
typedef __attribute__((ext_vector_type(4))) short s16x4;

static __device__ __forceinline__ short f2bf(float f) {
    union { float f; unsigned u; } v; v.f = f;
    unsigned r = v.u + 0x7fffu + ((v.u >> 16) & 1u);   // RNE
    return (short)(r >> 16);
}
static __device__ __forceinline__ float bf2f(short s) {
    union { float f; unsigned u; } v; v.u = ((unsigned)(unsigned short)s) << 16;
    return v.f;
}

// barrier that does NOT drain vmcnt (validated round 14)
static __device__ __forceinline__ void bar_nodrain() {
    asm volatile("s_waitcnt lgkmcnt(0)\n\ts_barrier" ::: "memory");
}

// ---------------- Yt[t][j][n] (bf16) = X[t][n][j] transposed, j in [0,128) ----------------
__global__ __launch_bounds__(256) void pack_yt(const float* __restrict__ feat,
                                               short* __restrict__ yt) {
    __shared__ float tile[32][33];
    const int t = blockIdx.z, j0 = blockIdx.y * 32, n0 = blockIdx.x * 32;
    const float* src = feat + (size_t)t * N_ * 128 + j0;
    const int jj = threadIdx.x & 31, i4 = threadIdx.x >> 5;
#pragma unroll
    for (int s = 0; s < 4; s++) {
        int ii = i4 * 4 + s;
        tile[ii][jj] = src[(size_t)(n0 + ii) * 128 + jj];
    }
    __syncthreads();
    const int nn = threadIdx.x & 31, j4 = threadIdx.x >> 5;
#pragma unroll
    for (int s = 0; s < 4; s++) {
        int j2 = j4 * 4 + s;
        yt[(size_t)(t * 128 + j0 + j2) * N_ + n0 + nn] = f2bf(tile[nn][j2]);
    }
}

// ---------------- PX[t] = P[t] @ X[t]   (bf16 MFMA, fp32 acc; N=128) ----------------
__global__ __launch_bounds__(512) void pfy_gemm(const float* __restrict__ P,
                                                const short* __restrict__ Yt,
                                                float* __restrict__ Z) {
    __shared__ short As[2][128][72];   // [buf][row][k], 144B stride
    __shared__ short Bs[2][128][72];   // [buf][col][k]
    const int t = blockIdx.y;
    const int m0 = blockIdx.x * 128;
    const int tid = threadIdx.x;
    const int lane = tid & 63, wid = tid >> 6;
    const int wm = wid >> 2, wn = wid & 3;       // wave grid 2(M) x 4(N)
    const int frow = lane & 15, kq = lane >> 4;  // MFMA fragment coords

    const float* Pt = P + (size_t)t * N_ * N_;
    const short* Bt = Yt + (size_t)t * 128 * N_;

    const int ar = tid >> 2;           // A row 0..127
    const int ak16 = (tid & 3) * 16;   // k offset (floats)
    const int bj = tid >> 2;           // B row 0..127
    const int bk16 = (tid & 3) * 16;   // k offset (shorts)

    f32x4 acc[4][2];
    f32x4 zf = {0.f, 0.f, 0.f, 0.f};
#pragma unroll
    for (int m = 0; m < 4; m++)
#pragma unroll
        for (int n = 0; n < 2; n++) acc[m][n] = zf;

    f32x4 aA[4], aB[4]; s16x8 bA[2], bB[2];

    const float* Pr = &Pt[(size_t)(m0 + ar) * 4096 + ak16];
    const short* Br = &Bt[(size_t)bj * 4096 + bk16];

#define LOADA(KT) do { const int k0_ = (KT) * 64;                              \
        _Pragma("unroll") for (int i = 0; i < 4; i++)                          \
            aA[i] = *(const f32x4*)&Pr[k0_ + i * 4];                           \
        _Pragma("unroll") for (int i = 0; i < 2; i++)                          \
            bA[i] = *(const s16x8*)&Br[k0_ + i * 8]; } while (0)
#define LOADB(KT) do { const int k0_ = (KT) * 64;                              \
        _Pragma("unroll") for (int i = 0; i < 4; i++)                          \
            aB[i] = *(const f32x4*)&Pr[k0_ + i * 4];                           \
        _Pragma("unroll") for (int i = 0; i < 2; i++)                          \
            bB[i] = *(const s16x8*)&Br[k0_ + i * 8]; } while (0)
#define STOREA(BUF) do {                                                       \
        _Pragma("unroll") for (int i = 0; i < 4; i++) {                        \
            s16x4 c4_;                                                         \
            _Pragma("unroll") for (int j = 0; j < 4; j++) c4_[j] = f2bf(aA[i][j]); \
            *(s16x4*)&As[BUF][ar][ak16 + i * 4] = c4_; }                       \
        _Pragma("unroll") for (int i = 0; i < 2; i++)                          \
            *(s16x8*)&Bs[BUF][bj][bk16 + i * 8] = bA[i]; } while (0)
#define STOREB(BUF) do {                                                       \
        _Pragma("unroll") for (int i = 0; i < 4; i++) {                        \
            s16x4 c4_;                                                         \
            _Pragma("unroll") for (int j = 0; j < 4; j++) c4_[j] = f2bf(aB[i][j]); \
            *(s16x4*)&As[BUF][ar][ak16 + i * 4] = c4_; }                       \
        _Pragma("unroll") for (int i = 0; i < 2; i++)                          \
            *(s16x8*)&Bs[BUF][bj][bk16 + i * 8] = bB[i]; } while (0)

    auto compute_t = [&](int buf) {
#pragma unroll
        for (int ks = 0; ks < 2; ks++) {
            s16x8 af[4], bfr[2];
#pragma unroll
            for (int m = 0; m < 4; m++)
                af[m] = *(const s16x8*)&As[buf][wm * 64 + m * 16 + frow][kq * 8 + ks * 32];
#pragma unroll
            for (int n = 0; n < 2; n++)
                bfr[n] = *(const s16x8*)&Bs[buf][wn * 32 + n * 16 + frow][kq * 8 + ks * 32];
#pragma unroll
            for (int m = 0; m < 4; m++)
#pragma unroll
                for (int n = 0; n < 2; n++)
                    acc[m][n] = __builtin_amdgcn_mfma_f32_16x16x32_bf16(af[m], bfr[n], acc[m][n], 0, 0, 0);
        }
    };

    LOADA(0);
    STOREA(0);
    LOADB(1);
    LOADA(2);
    bar_nodrain();

#pragma unroll 2
    for (int kt = 0; kt < 64; kt++) {
        compute_t(kt & 1);
        if (kt < 63) {
            if ((kt & 1) == 0) {
                STOREB(1);
                if (kt + 3 < 64) LOADB(kt + 3);
            } else {
                STOREA(0);
                if (kt + 3 < 64) LOADA(kt + 3);
            }
            bar_nodrain();
        }
    }
#undef LOADA
#undef LOADB
#undef STOREA
#undef STOREB

    float* Zt = Z + (size_t)t * N_ * 128;
#pragma unroll
    for (int m = 0; m < 4; m++)
#pragma unroll
        for (int n = 0; n < 2; n++)
#pragma unroll
            for (int r = 0; r < 4; r++) {
                int row = m0 + wm * 64 + m * 16 + kq * 4 + r;  // C/D: row=(lane>>4)*4+reg
                int col = wn * 32 + n * 16 + frow;             //      col=lane&15
                Zt[(size_t)row * 128 + col] = acc[m][n][r];
            }
}

// ---------------- MFMA filter heads (bf16 hi/lo A, exact to ~2^-17) ----------------
// mode 0: low = relu(PX@Wlp + b_lpf) -> xseq[:, :128]
// mode 1: high = relu((X-PX)@Whp + b_hpf) -> xseq[:, 128:]
// Output: xhi only (bf16) — the LSTM consumes bf16 activations.
__global__ __launch_bounds__(512) void hp2m(const float* __restrict__ feat,
                                            const float* __restrict__ PX,
                                            const short* __restrict__ wlpT_hi,
                                            const short* __restrict__ wlpT_lo,
                                            const short* __restrict__ whpT_hi,
                                            const short* __restrict__ whpT_lo,
                                            const float* __restrict__ b_lpf,
                                            const float* __restrict__ b_hpf,
                                            short* __restrict__ xhi) {
    __shared__ short Ah[2][128][40], Al[2][128][40];
    __shared__ short Bh[2][128][40], Bl[2][128][40];
    const int m0 = blockIdx.x * 128;
    const int mode = blockIdx.y;
    const short* wT_hi = mode ? whpT_hi : wlpT_hi;
    const short* wT_lo = mode ? whpT_lo : wlpT_lo;
    const float* bp = mode ? b_hpf : b_lpf;
    const int tid = threadIdx.x;
    const int lane = tid & 63, wid = tid >> 6;
    const int wm = wid >> 2, wn = wid & 3;
    const int frow = lane & 15, kq = lane >> 4;
    const int sr = tid >> 2;            // staging row 0..127
    const int sk8 = (tid & 3) * 8;      // k offset within 32

    f32x4 acc[4][2];
    f32x4 zf = {0.f, 0.f, 0.f, 0.f};
#pragma unroll
    for (int m = 0; m < 4; m++)
#pragma unroll
        for (int n = 0; n < 2; n++) acc[m][n] = zf;

    f32x4 v0, v1; s16x8 b_h, b_l;

    auto load_t = [&](int kt) {
        const int k0 = kt * 32;
        const size_t abase = (size_t)(m0 + sr) * 128 + k0 + sk8;
        v0 = *(const f32x4*)&PX[abase];
        v1 = *(const f32x4*)&PX[abase + 4];
        if (mode) {
            f32x4 f0 = *(const f32x4*)&feat[abase];
            f32x4 f1 = *(const f32x4*)&feat[abase + 4];
#pragma unroll
            for (int i = 0; i < 4; i++) { v0[i] = f0[i] - v0[i]; v1[i] = f1[i] - v1[i]; }
        }
        const size_t bb = (size_t)sr * 128 + k0 + sk8;
        b_h = *(const s16x8*)&wT_hi[bb];
        b_l = *(const s16x8*)&wT_lo[bb];
    };
    auto store_t = [&](int buf) {
        s16x8 hi8, lo8;
#pragma unroll
        for (int i = 0; i < 4; i++) {
            hi8[i] = f2bf(v0[i]);     lo8[i] = f2bf(v0[i] - bf2f(hi8[i]));
            hi8[i + 4] = f2bf(v1[i]); lo8[i + 4] = f2bf(v1[i] - bf2f(hi8[i + 4]));
        }
        *(s16x8*)&Ah[buf][sr][sk8] = hi8;
        *(s16x8*)&Al[buf][sr][sk8] = lo8;
        *(s16x8*)&Bh[buf][sr][sk8] = b_h;
        *(s16x8*)&Bl[buf][sr][sk8] = b_l;
    };
    auto compute_t = [&](int buf) {
        s16x8 afh[4], afl[4], bfh[2], bfl[2];
#pragma unroll
        for (int m = 0; m < 4; m++) {
            afh[m] = *(const s16x8*)&Ah[buf][wm * 64 + m * 16 + frow][kq * 8];
            afl[m] = *(const s16x8*)&Al[buf][wm * 64 + m * 16 + frow][kq * 8];
        }
#pragma unroll
        for (int n = 0; n < 2; n++) {
            bfh[n] = *(const s16x8*)&Bh[buf][wn * 32 + n * 16 + frow][kq * 8];
            bfl[n] = *(const s16x8*)&Bl[buf][wn * 32 + n * 16 + frow][kq * 8];
        }
#pragma unroll
        for (int m = 0; m < 4; m++)
#pragma unroll
            for (int n = 0; n < 2; n++) {
                acc[m][n] = __builtin_amdgcn_mfma_f32_16x16x32_bf16(afh[m], bfh[n], acc[m][n], 0, 0, 0);
                acc[m][n] = __builtin_amdgcn_mfma_f32_16x16x32_bf16(afh[m], bfl[n], acc[m][n], 0, 0, 0);
                acc[m][n] = __builtin_amdgcn_mfma_f32_16x16x32_bf16(afl[m], bfh[n], acc[m][n], 0, 0, 0);
            }
    };

    load_t(0);
    store_t(0);
    bar_nodrain();
#pragma unroll
    for (int kt = 0; kt < 4; kt++) {
        const int cur = kt & 1;
        if (kt < 3) load_t(kt + 1);
        compute_t(cur);
        bar_nodrain();
        if (kt < 3) { store_t(cur ^ 1); bar_nodrain(); }
    }

    // epilogue: bias + relu -> bf16 (hi only)
    float bv[2];
#pragma unroll
    for (int n = 0; n < 2; n++) bv[n] = bp[wn * 32 + n * 16 + frow];
#pragma unroll
    for (int m = 0; m < 4; m++)
#pragma unroll
        for (int n = 0; n < 2; n++)
#pragma unroll
            for (int r = 0; r < 4; r++) {
                int row = m0 + wm * 64 + m * 16 + kq * 4 + r;
                int col = wn * 32 + n * 16 + frow;
                float val = fmaxf(acc[m][n][r] + bv[n], 0.f);
                xhi[(size_t)row * 256 + mode * 128 + col] = f2bf(val);
            }
}

// ---------------- merged packs: [0,512)=wc, [512,640)=w1c, 640=bias, [641,673)=wT ----------------
__global__ __launch_bounds__(256) void pack_all(const float* __restrict__ W1,
                                                const float* __restrict__ W_ih,
                                                const float* __restrict__ W_hh,
                                                const float* __restrict__ b_ih,
                                                const float* __restrict__ b_hh,
                                                const float* __restrict__ W_lpf,
                                                const float* __restrict__ W_hpf,
                                                short* __restrict__ w1chi,
                                                short* __restrict__ w1clo,
                                                short* __restrict__ wchi,
                                                short* __restrict__ wclo,
                                                float* __restrict__ bsum,
                                                short* __restrict__ wlpT_hi,
                                                short* __restrict__ wlpT_lo,
                                                short* __restrict__ whpT_hi,
                                                short* __restrict__ whpT_lo) {
    __shared__ float tile[32][33];
    const int b = blockIdx.x;
    if (b < 512) {
        int idx = (b * 256 + threadIdx.x) * 4;
        int j = idx >> 9, k = idx & 511;
        int orig = (j & 3) * 256 + (j >> 2);
        const float* src = (k < 256) ? &W_ih[(size_t)orig * 256 + k]
                                     : &W_hh[(size_t)orig * 256 + (k - 256)];
        f32x4 v = *(const f32x4*)src;
        s16x4 hi, lo;
#pragma unroll
        for (int i = 0; i < 4; i++) {
            hi[i] = f2bf(v[i]);
            lo[i] = f2bf(v[i] - bf2f(hi[i]));
        }
        *(s16x4*)&wchi[idx] = hi;
        *(s16x4*)&wclo[idx] = lo;
    } else if (b < 640) {
        const int bb = b - 512;
        const int k0 = (bb & 7) * 32;
        const int j0 = (bb >> 3) * 32;
        const int koff = (j0 >= 256) ? 256 : 0;
        const int joff = (j0 >= 256) ? 256 : 0;
        const int jj = threadIdx.x & 31, k4 = threadIdx.x >> 5;
#pragma unroll
        for (int s = 0; s < 4; s++) {
            int kk = k4 * 4 + s;
            tile[kk][jj] = W1[(size_t)(k0 + kk + koff) * 256 + (j0 + jj - joff)];
        }
        __syncthreads();
        const int kk2 = threadIdx.x & 31, j4 = threadIdx.x >> 5;
#pragma unroll
        for (int s = 0; s < 4; s++) {
            int j2 = j4 * 4 + s;
            float v = tile[kk2][j2];
            short hb = f2bf(v);
            w1chi[(size_t)(j0 + j2) * 256 + k0 + kk2] = hb;
            w1clo[(size_t)(j0 + j2) * 256 + k0 + kk2] = f2bf(v - bf2f(hb));
        }
    } else if (b == 640) {
#pragma unroll
        for (int s = 0; s < 4; s++) {
            int j = s * 256 + threadIdx.x;
            int orig = (j & 3) * 256 + (j >> 2);
            bsum[j] = b_ih[orig] + b_hh[orig];
        }
    } else {
        const int bb2 = b - 641;
        const int wsel = bb2 >> 4;
        const int t16 = bb2 & 15;
        const int k0 = (t16 & 3) * 32;
        const int j0 = (t16 >> 2) * 32;
        const float* Wsrc = wsel ? W_hpf : W_lpf;
        short* dhi = wsel ? whpT_hi : wlpT_hi;
        short* dlo = wsel ? whpT_lo : wlpT_lo;
        const int jj = threadIdx.x & 31, k4 = threadIdx.x >> 5;
#pragma unroll
        for (int s = 0; s < 4; s++) {
            int kk = k4 * 4 + s;
            tile[kk][jj] = Wsrc[(size_t)(k0 + kk) * 128 + (j0 + jj)];
        }
        __syncthreads();
        const int kk2 = threadIdx.x & 31, j4 = threadIdx.x >> 5;
#pragma unroll
        for (int s = 0; s < 4; s++) {
            int j2 = j4 * 4 + s;
            float v = tile[kk2][j2];
            short hb = f2bf(v);
            dhi[(size_t)(j0 + j2) * 128 + k0 + kk2] = hb;
            dlo[(size_t)(j0 + j2) * 128 + k0 + kk2] = f2bf(v - bf2f(hb));
        }
    }
}

// ---------------- fused LSTM step: bf16-activation GEMM (2 MFMA terms) + pointwise ----------------
// gates ~= bf16(a) @ (Wh + Wl): activations bf16-rounded (~2^-9), weights exact hi/lo.
// nkt=8 & czero for t=0 (h==0, c==0). hlo written only when wlo!=0 (t=7, for uv_gemm).
__global__ __launch_bounds__(512) void lstm_step(const short* __restrict__ xhi,
                                                 const short* __restrict__ hhi_r,
                                                 const short* __restrict__ wchi,
                                                 const short* __restrict__ wclo,
                                                 const float* __restrict__ bsum,
                                                 float* __restrict__ cbuf,
                                                 short* __restrict__ hhi_w,
                                                 short* __restrict__ hlo_w,
                                                 int nkt, int czero, int wlo) {
    __shared__ short Ah[2][128][40];
    __shared__ short Bh[2][128][40], Bl[2][128][40];
    __shared__ float gl[128][132];     // 16B-aligned row stride (528 B)
    const int m0 = blockIdx.x * 128;
    const int j0 = blockIdx.y * 128;
    const int tid = threadIdx.x;
    const int lane = tid & 63, wid = tid >> 6;
    const int wm = wid >> 2, wn = wid & 3;
    const int frow = lane & 15, kq = lane >> 4;

    const int sr = tid >> 2;
    const int sk8 = (tid & 3) * 8;

    f32x4 acc[4][2];
    f32x4 zf = {0.f, 0.f, 0.f, 0.f};
#pragma unroll
    for (int m = 0; m < 4; m++)
#pragma unroll
        for (int n = 0; n < 2; n++) acc[m][n] = zf;

    s16x8 a_h, b_h, b_l;

    auto load_t = [&](int kt) {
        const int k0 = kt * 32;
        const short* ah = (k0 < 256) ? xhi : hhi_r;
        const size_t abase = (size_t)(m0 + sr) * 256 + (k0 & 255) + sk8;
        a_h = *(const s16x8*)&ah[abase];
        const size_t bb = (size_t)(j0 + sr) * 512 + k0 + sk8;
        b_h = *(const s16x8*)&wchi[bb];
        b_l = *(const s16x8*)&wclo[bb];
    };
    auto store_t = [&](int buf) {
        *(s16x8*)&Ah[buf][sr][sk8] = a_h;
        *(s16x8*)&Bh[buf][sr][sk8] = b_h;
        *(s16x8*)&Bl[buf][sr][sk8] = b_l;
    };
    auto compute_t = [&](int buf) {
        s16x8 afh[4], bfh[2], bfl[2];
#pragma unroll
        for (int m = 0; m < 4; m++)
            afh[m] = *(const s16x8*)&Ah[buf][wm * 64 + m * 16 + frow][kq * 8];
#pragma unroll
        for (int n = 0; n < 2; n++) {
            bfh[n] = *(const s16x8*)&Bh[buf][wn * 32 + n * 16 + frow][kq * 8];
            bfl[n] = *(const s16x8*)&Bl[buf][wn * 32 + n * 16 + frow][kq * 8];
        }
#pragma unroll
        for (int m = 0; m < 4; m++)
#pragma unroll
            for (int n = 0; n < 2; n++) {
                acc[m][n] = __builtin_amdgcn_mfma_f32_16x16x32_bf16(afh[m], bfh[n], acc[m][n], 0, 0, 0);
                acc[m][n] = __builtin_amdgcn_mfma_f32_16x16x32_bf16(afh[m], bfl[n], acc[m][n], 0, 0, 0);
            }
    };

    load_t(0);
    store_t(0);
    bar_nodrain();
#pragma unroll 2
    for (int kt = 0; kt < nkt; kt++) {
        const int cur = kt & 1;
        if (kt < nkt - 1) load_t(kt + 1);
        compute_t(cur);
        bar_nodrain();
        if (kt < nkt - 1) { store_t(cur ^ 1); bar_nodrain(); }
    }

    // epilogue: acc -> gl tile (distinct LDS array)
#pragma unroll
    for (int m = 0; m < 4; m++)
#pragma unroll
        for (int n = 0; n < 2; n++)
#pragma unroll
            for (int r = 0; r < 4; r++)
                gl[wm * 64 + m * 16 + kq * 4 + r][wn * 32 + n * 16 + frow] = acc[m][n][r];
    bar_nodrain();

    // pointwise: thread -> (row, 8 channels); gates i,f,g,o adjacent in packed cols
    const int erow = tid >> 2;
    const int ec0 = (tid & 3) * 8;
    const size_t cbase = (size_t)(m0 + erow) * 256 + blockIdx.y * 32 + ec0;
    f32x4 co0 = {0.f, 0.f, 0.f, 0.f}, co1 = {0.f, 0.f, 0.f, 0.f};
    if (!czero) {
        co0 = *(const f32x4*)&cbuf[cbase];
        co1 = *(const f32x4*)&cbuf[cbase + 4];
    }
    f32x4 cn0, cn1;
    s16x8 h8, l8;
#pragma unroll
    for (int i = 0; i < 8; i++) {
        f32x4 g4 = *(const f32x4*)&gl[erow][(ec0 + i) * 4];
        f32x4 bs = *(const f32x4*)&bsum[j0 + (ec0 + i) * 4];
        float si = 1.f / (1.f + expf(-(g4[0] + bs[0])));
        float sf = 1.f / (1.f + expf(-(g4[1] + bs[1])));
        float tg = tanhf(g4[2] + bs[2]);
        float so = 1.f / (1.f + expf(-(g4[3] + bs[3])));
        float cold = (i < 4) ? co0[i] : co1[i - 4];
        float cn = sf * cold + si * tg;
        float hv = so * tanhf(cn);
        if (i < 4) cn0[i] = cn; else cn1[i - 4] = cn;
        h8[i] = f2bf(hv);
        l8[i] = f2bf(hv - bf2f(h8[i]));
    }
    *(f32x4*)&cbuf[cbase] = cn0;
    *(f32x4*)&cbuf[cbase + 4] = cn1;
    *(s16x8*)&hhi_w[cbase] = h8;
    if (wlo) *(s16x8*)&hlo_w[cbase] = l8;
}

// ---------------- UV = h @ Bc^T  (M=4096, K=256, N=512; full 3-term hi/lo) ----------------
__global__ __launch_bounds__(512) void uv_gemm(const short* __restrict__ hhi,
                                               const short* __restrict__ hlo,
                                               const short* __restrict__ whi,
                                               const short* __restrict__ wlo,
                                               float* __restrict__ UV) {
    __shared__ short Ah[2][128][40], Al[2][128][40];
    __shared__ short Bh[2][128][40], Bl[2][128][40];
    const int m0 = blockIdx.x * 128;
    const int j0 = blockIdx.y * 128;
    const int tid = threadIdx.x;
    const int lane = tid & 63, wid = tid >> 6;
    const int wm = wid >> 2, wn = wid & 3;
    const int frow = lane & 15, kq = lane >> 4;
    const int sr = tid >> 2;
    const int sk8 = (tid & 3) * 8;

    f32x4 acc[4][2];
    f32x4 zf = {0.f, 0.f, 0.f, 0.f};
#pragma unroll
    for (int m = 0; m < 4; m++)
#pragma unroll
        for (int n = 0; n < 2; n++) acc[m][n] = zf;

    s16x8 a_h, a_l, b_h, b_l;

    auto load_t = [&](int kt) {
        const int k0 = kt * 32;
        const size_t abase = (size_t)(m0 + sr) * 256 + k0 + sk8;
        a_h = *(const s16x8*)&hhi[abase];
        a_l = *(const s16x8*)&hlo[abase];
        const size_t bb = (size_t)(j0 + sr) * 256 + k0 + sk8;
        b_h = *(const s16x8*)&whi[bb];
        b_l = *(const s16x8*)&wlo[bb];
    };
    auto store_t = [&](int buf) {
        *(s16x8*)&Ah[buf][sr][sk8] = a_h;
        *(s16x8*)&Al[buf][sr][sk8] = a_l;
        *(s16x8*)&Bh[buf][sr][sk8] = b_h;
        *(s16x8*)&Bl[buf][sr][sk8] = b_l;
    };
    auto compute_t = [&](int buf) {
        s16x8 afh[4], afl[4], bfh[2], bfl[2];
#pragma unroll
        for (int m = 0; m < 4; m++) {
            afh[m] = *(const s16x8*)&Ah[buf][wm * 64 + m * 16 + frow][kq * 8];
            afl[m] = *(const s16x8*)&Al[buf][wm * 64 + m * 16 + frow][kq * 8];
        }
#pragma unroll
        for (int n = 0; n < 2; n++) {
            bfh[n] = *(const s16x8*)&Bh[buf][wn * 32 + n * 16 + frow][kq * 8];
            bfl[n] = *(const s16x8*)&Bl[buf][wn * 32 + n * 16 + frow][kq * 8];
        }
#pragma unroll
        for (int m = 0; m < 4; m++)
#pragma unroll
            for (int n = 0; n < 2; n++) {
                acc[m][n] = __builtin_amdgcn_mfma_f32_16x16x32_bf16(afh[m], bfh[n], acc[m][n], 0, 0, 0);
                acc[m][n] = __builtin_amdgcn_mfma_f32_16x16x32_bf16(afh[m], bfl[n], acc[m][n], 0, 0, 0);
                acc[m][n] = __builtin_amdgcn_mfma_f32_16x16x32_bf16(afl[m], bfh[n], acc[m][n], 0, 0, 0);
            }
    };

    load_t(0);
    store_t(0);
    bar_nodrain();
#pragma unroll 2
    for (int kt = 0; kt < 8; kt++) {
        const int cur = kt & 1;
        if (kt < 7) load_t(kt + 1);
        compute_t(cur);
        bar_nodrain();
        if (kt < 7) { store_t(cur ^ 1); bar_nodrain(); }
    }

#pragma unroll
    for (int m = 0; m < 4; m++)
#pragma unroll
        for (int n = 0; n < 2; n++)
#pragma unroll
            for (int r = 0; r < 4; r++) {
                int row = m0 + wm * 64 + m * 16 + kq * 4 + r;
                int col = j0 + wn * 32 + n * 16 + frow;
                UV[(size_t)row * 512 + col] = acc[m][n][r];
            }
}

// ---------------- per-edge: logit = relu(U[src]+V[dst]+b1) . W2 + b2 ----------------
__global__ __launch_bounds__(256) void mlp_edge(const float* __restrict__ UV,
                                                const int* __restrict__ eidx,
                                                const float* __restrict__ b1,
                                                const float* __restrict__ W2,
                                                const float* __restrict__ b2,
                                                float* __restrict__ out) {
    const int e = blockIdx.x * 4 + (threadIdx.x >> 6);
    const int lane = threadIdx.x & 63;
    const int c4 = lane * 4;
    const int src = eidx[e];
    const int dst = eidx[E_ + e];
    f32x4 u = *(const f32x4*)&UV[(size_t)src * 512 + c4];
    f32x4 v = *(const f32x4*)&UV[(size_t)dst * 512 + 256 + c4];
    f32x4 bb = *(const f32x4*)&b1[c4];
    f32x4 ww = *(const f32x4*)&W2[c4];
    float p = 0.f;
#pragma unroll
    for (int i = 0; i < 4; i++)
        p += fmaxf(u[i] + v[i] + bb[i], 0.f) * ww[i];
    p += __shfl_xor(p, 1);
    p += __shfl_xor(p, 2);
    p += __shfl_xor(p, 4);
    p += __shfl_xor(p, 8);
    p += __shfl_xor(p, 16);
    p += __shfl_xor(p, 32);
    if (lane == 0) out[e] = p + b2[0];
}

extern "C" void kernel_launch(void* const* d_in, const int* in_sizes, int n_in,
                              void* d_out, int out_size, void* d_ws, size_t ws_size,
                              hipStream_t stream) {
    (void)in_sizes; (void)n_in; (void)out_size; (void)ws_size;
    const float* feat  = (const float*)d_in[0];
    const float* P     = (const float*)d_in[1];
    const int*   eidx  = (const int*)d_in[2];
    const float* W_lpf = (const float*)d_in[3];
    const float* b_lpf = (const float*)d_in[4];
    const float* W_hpf = (const float*)d_in[5];
    const float* b_hpf = (const float*)d_in[6];
    const float* W_ih  = (const float*)d_in[7];
    const float* W_hh  = (const float*)d_in[8];
    const float* b_ih  = (const float*)d_in[9];
    const float* b_hh  = (const float*)d_in[10];
    const float* W1    = (const float*)d_in[11];
    const float* b1    = (const float*)d_in[12];
    const float* W2    = (const float*)d_in[13];
    const float* b2    = (const float*)d_in[14];
    float* out = (float*)d_out;

    // workspace layout (100.7 MB)
    char* ws = (char*)d_ws;
    char*  pkreg = ws;           ws += (size_t)T_ * N_ * 128 * 4;   // 16.78 MB: weight packs
    char*  ytreg = ws;           ws += (size_t)T_ * 256 * N_ * 2;   // 16.78 MB; yt then c + h dbuf
    char*  Zreg  = ws;           ws += (size_t)T_ * N_ * 256 * 4;   // 33.55 MB; PX then UV
    short* xhi   = (short*)ws;   ws += (size_t)T_ * N_ * 256 * 2;   // 16.78 MB
    ws += (size_t)T_ * N_ * 256 * 2;                                 // (xlo region unused)

    // packs in pkreg (built first, independent of PX)
    short* w1chi = (short*)pkreg;
    short* w1clo = w1chi + (size_t)512 * 256;
    short* wchi  = w1clo + (size_t)512 * 256;
    short* wclo  = wchi + (size_t)1024 * 512;
    float* bsum  = (float*)(wclo + (size_t)1024 * 512);
    short* wlpT_hi = (short*)(bsum + 1024);
    short* wlpT_lo = wlpT_hi + 128 * 128;
    short* whpT_hi = wlpT_lo + 128 * 128;
    short* whpT_lo = whpT_hi + 128 * 128;

    short* yt    = (short*)ytreg;                 // 8.4 MB, dead after pfy
    float* PX    = (float*)Zreg;                  // 16.8 MB, dead after hp2m
    // ytreg after pfy: c (4 MB) + h double-buffer pairs (4 x 2 MB)
    float* cbuf  = (float*)ytreg;
    short* hhi0  = (short*)(ytreg + (size_t)N_ * 256 * 4);
    short* hlo0  = hhi0 + (size_t)N_ * 256;
    short* hhi1  = hlo0 + (size_t)N_ * 256;
    short* hlo1  = hhi1 + (size_t)N_ * 256;
    float* UV    = (float*)Zreg;                  // reuse Zreg after PX dead

    pack_all<<<dim3(673), 256, 0, stream>>>(W1, W_ih, W_hh, b_ih, b_hh, W_lpf, W_hpf,
                                            w1chi, w1clo, wchi, wclo, bsum,
                                            wlpT_hi, wlpT_lo, whpT_hi, whpT_lo);
    pack_yt<<<dim3(N_ / 32, 4, T_), 256, 0, stream>>>(feat, yt);
    pfy_gemm<<<dim3(N_ / 128, T_), 512, 0, stream>>>(P, yt, PX);
    hp2m<<<dim3(T_ * N_ / 128, 2), 512, 0, stream>>>(feat, PX, wlpT_hi, wlpT_lo,
                                                     whpT_hi, whpT_lo, b_lpf, b_hpf,
                                                     xhi);

    for (int t = 0; t < T_; t++) {
        const short* hr_hi = (t & 1) ? hhi1 : hhi0;
        short* hw_hi = (t & 1) ? hhi0 : hhi1;
        short* hw_lo = (t & 1) ? hlo0 : hlo1;
        lstm_step<<<dim3(N_ / 128, 1024 / 128), 512, 0, stream>>>(
            xhi + (size_t)t * N_ * 256, hr_hi, wchi, wclo, bsum, cbuf, hw_hi, hw_lo,
            (t == 0) ? 8 : 16, (t == 0) ? 1 : 0, (t == T_ - 1) ? 1 : 0);
    }
    // t=7 (odd) wrote pair 0 -> final h is hhi0/hlo0

    uv_gemm<<<dim3(N_ / 128, 512 / 128), 512, 0, stream>>>(hhi0, hlo0, w1chi, w1clo, UV);
    mlp_edge<<<dim3(E_ / 4), 256, 0, stream>>>(UV, eidx, b1, W2, b2, out);
}